// Round 8
// baseline (282.354 us; speedup 1.0000x reference)
//
#include <hip/hip_runtime.h>

// UniGCNConv2 via on-device bucketed counting sort (packed 32-bit keys, no
// global atomics), gather-based segment sums with CONVERGENT index-prefetch:
// one coalesced perm read per segment; __shfl executed with all 64 lanes
// active (uniform loop bound), loads predicated. All-f32 numerics.
// N=100000, M=200000, E=1e6, D_IN=64, out 128.

#define DIN 64
#define DOUT 128
#define CH 4096          // pairs per chunk for P1/P2
#define BSHIFT 10        // coarse bucket = key >> 10 (fine range 1024)
#define PAYBITS 18
#define PAYMASK ((1u << PAYBITS) - 1u)

// ---- P1: per-chunk coarse-bucket histogram (combined E and V tables) ----
__global__ __launch_bounds__(256) void p1_hist(
    const int* __restrict__ vertex, const int* __restrict__ edges,
    int* __restrict__ G, int E, int BKE, int BK, int NCH) {
  __shared__ int h[512];
  for (int i = threadIdx.x; i < BK; i += 256) h[i] = 0;
  __syncthreads();
  int c = blockIdx.x;
  int s = c * CH, e_ = min(E, s + CH);
  for (int i = s + threadIdx.x; i < e_; i += 256) {
    atomicAdd(&h[edges[i] >> BSHIFT], 1);
    atomicAdd(&h[BKE + (vertex[i] >> BSHIFT)], 1);
  }
  __syncthreads();
  for (int b = threadIdx.x; b < BK; b += 256) G[(size_t)b * NCH + c] = h[b];
}

// ---- P1b: exclusive scan of each bucket row across chunks; rowTot[b] = total ----
__global__ __launch_bounds__(256) void p1b_rowscan(
    int* __restrict__ G, int* __restrict__ rowTot, int NCH) {
  int b = blockIdx.x;
  int* row = G + (size_t)b * NCH;
  __shared__ int wsum[4];
  __shared__ int carry;
  if (threadIdx.x == 0) carry = 0;
  __syncthreads();
  for (int base = 0; base < NCH; base += 256) {
    int i = base + threadIdx.x;
    int v = (i < NCH) ? row[i] : 0;
    int lane = threadIdx.x & 63, wid = threadIdx.x >> 6;
    int inc = v;
    #pragma unroll
    for (int o = 1; o < 64; o <<= 1) {
      int t = __shfl_up(inc, o);
      if (lane >= o) inc += t;
    }
    if (lane == 63) wsum[wid] = inc;
    __syncthreads();
    int woff = carry;
    for (int w = 0; w < wid; ++w) woff += wsum[w];
    int excl = woff + inc - v;
    if (i < NCH) row[i] = excl;
    __syncthreads();
    if (threadIdx.x == 0) carry += wsum[0] + wsum[1] + wsum[2] + wsum[3];
    __syncthreads();
  }
  if (threadIdx.x == 0) rowTot[b] = carry;
}

// ---- P1c: exclusive scan of bucket totals -> absolute bucket bases (+ sentinel) ----
__global__ void p1c_scan(const int* __restrict__ rowTot,
                         int* __restrict__ bucketBase, int BK) {
  if (threadIdx.x == 0 && blockIdx.x == 0) {
    int s = 0;
    for (int b = 0; b < BK; ++b) { bucketBase[b] = s; s += rowTot[b]; }
    bucketBase[BK] = s;
  }
}

// ---- P2: scatter packed (fine,payload) into bucket-partitioned temp via LDS cursors ----
__global__ __launch_bounds__(256) void p2_scatter(
    const int* __restrict__ vertex, const int* __restrict__ edges,
    const int* __restrict__ G, const int* __restrict__ bucketBase,
    unsigned* __restrict__ temp, int E, int BKE, int BK, int NCH) {
  __shared__ int curs[512];
  int c = blockIdx.x;
  for (int b = threadIdx.x; b < BK; b += 256)
    curs[b] = bucketBase[b] + G[(size_t)b * NCH + c];
  __syncthreads();
  int s = c * CH, e_ = min(E, s + CH);
  for (int i = s + threadIdx.x; i < e_; i += 256) {
    int e = edges[i], v = vertex[i];
    int pE = atomicAdd(&curs[e >> BSHIFT], 1);
    temp[pE] = ((unsigned)(e & 1023) << PAYBITS) | (unsigned)v;
    int pV = atomicAdd(&curs[BKE + (v >> BSHIFT)], 1);
    temp[pV] = ((unsigned)(v & 1023) << PAYBITS) | (unsigned)e;
  }
}

// ---- P3: per-bucket fine counting sort; writes off[] (inclusive ends) and perm ----
__global__ __launch_bounds__(256) void p3_sort(
    const unsigned* __restrict__ temp, const int* __restrict__ bucketBase,
    int* __restrict__ off, int* __restrict__ perm, int BKE, int M, int N) {
  __shared__ int hist[1024];
  __shared__ int pos[1024];
  __shared__ int wsum[4];
  int g = blockIdx.x;
  bool isE = g < BKE;
  int gg = isE ? g : g - BKE;
  int keyBase = gg << BSHIFT;
  int cap = isE ? M : N;
  int offBase = (isE ? 0 : M) + keyBase;
  int fineCount = min(1024, cap - keyBase);
  int pairBase = bucketBase[g], pairEnd = bucketBase[g + 1];
  int cnt = pairEnd - pairBase;

  for (int i = threadIdx.x; i < 1024; i += 256) hist[i] = 0;
  __syncthreads();
  for (int i = threadIdx.x; i < cnt; i += 256)
    atomicAdd(&hist[temp[pairBase + i] >> PAYBITS], 1);
  __syncthreads();

  int t4 = threadIdx.x * 4;
  int a0 = hist[t4], a1 = hist[t4 + 1], a2 = hist[t4 + 2], a3 = hist[t4 + 3];
  int tsum = a0 + a1 + a2 + a3;
  int lane = threadIdx.x & 63, wid = threadIdx.x >> 6;
  int inc = tsum;
  #pragma unroll
  for (int o = 1; o < 64; o <<= 1) {
    int t = __shfl_up(inc, o);
    if (lane >= o) inc += t;
  }
  if (lane == 63) wsum[wid] = inc;
  __syncthreads();
  int woff = 0;
  for (int w = 0; w < wid; ++w) woff += wsum[w];
  int excl = woff + inc - tsum;
  pos[t4] = excl; pos[t4 + 1] = excl + a0;
  pos[t4 + 2] = excl + a0 + a1; pos[t4 + 3] = excl + a0 + a1 + a2;
  __syncthreads();

  for (int f = threadIdx.x; f < fineCount; f += 256)
    off[offBase + f] = pairBase + pos[f] + hist[f];
  for (int f = threadIdx.x; f < 1024; f += 256) pos[f] += pairBase;
  __syncthreads();

  for (int i = threadIdx.x; i < cnt; i += 256) {
    unsigned p = temp[pairBase + i];
    int q = atomicAdd(&pos[p >> PAYBITS], 1);
    perm[q] = (int)(p & PAYMASK);
  }
}

// ---- compute passes (f32 throughout) ----

// one wave per hyperedge. Prefetch up to 64 indices with ONE coalesced perm
// read; distribute via __shfl executed CONVERGENTLY (uniform loop bound, all
// 64 lanes active); loads predicated per 16-lane group.
__global__ __launch_bounds__(256) void k_edge(
    const float* __restrict__ X, const int* __restrict__ off,
    const int* __restrict__ perm, const float* __restrict__ dege,
    float* __restrict__ Xe, int M) {
  long long gid = (long long)blockIdx.x * 256 + threadIdx.x;
  int e = (int)(gid >> 6);
  if (e >= M) return;
  int lane = threadIdx.x & 63;
  int g = lane >> 4, li = lane & 15;
  int start = e ? off[e - 1] : 0;
  int end = off[e];
  int deg = end - start;
  int myidx = (lane < deg) ? perm[start + lane] : 0;
  int jmax = min(deg, 64);
  const float4* X4 = (const float4*)X;
  float4 acc = make_float4(0.f, 0.f, 0.f, 0.f);
  for (int jj = 0; jj < jmax; jj += 4) {   // jj uniform across the wave
    int j = jj + g;
    int v0 = __shfl(myidx, j & 63);        // convergent: all lanes active
    if (j < jmax) {
      float4 a = X4[(size_t)v0 * 16 + li];
      acc.x += a.x; acc.y += a.y; acc.z += a.z; acc.w += a.w;
    }
  }
  for (int j2 = 64 + g; j2 < deg; j2 += 4) {  // rare tail: direct loads
    int v0 = perm[start + j2];
    float4 a = X4[(size_t)v0 * 16 + li];
    acc.x += a.x; acc.y += a.y; acc.z += a.z; acc.w += a.w;
  }
  #pragma unroll
  for (int o = 16; o <= 32; o <<= 1) {
    acc.x += __shfl_xor(acc.x, o);
    acc.y += __shfl_xor(acc.y, o);
    acc.z += __shfl_xor(acc.z, o);
    acc.w += __shfl_xor(acc.w, o);
  }
  if (g == 0) {
    float s = dege[e] / fmaxf((float)deg, 1.0f);
    float4 r = make_float4(acc.x * s, acc.y * s, acc.z * s, acc.w * s);
    ((float4*)Xe)[(size_t)e * 16 + li] = r;
  }
}

// one wave per node: convergent index-prefetch gather from f32 Xe, degv scale,
// L2 normalize, @W + b.
__global__ __launch_bounds__(512) void k_node(
    const float* __restrict__ Xe, const int* __restrict__ off,
    const int* __restrict__ perm, const float* __restrict__ degv,
    const float* __restrict__ W, const float* __restrict__ b,
    float* __restrict__ out, int N, int M) {
  __shared__ float Ws[DIN * DOUT];  // 32 KB
  for (int i = threadIdx.x; i < DIN * DOUT; i += 512) Ws[i] = W[i];
  __syncthreads();

  long long gid = (long long)blockIdx.x * 512 + threadIdx.x;
  int node = (int)(gid >> 6);
  if (node >= N) return;
  int lane = threadIdx.x & 63;
  int g = lane >> 4, li = lane & 15;

  int idx = M + node;
  int start = off[idx - 1];  // node 0 reads off[M-1] == E, the vertex-perm base
  int end = off[idx];
  int deg = end - start;
  int myidx = (lane < deg) ? perm[start + lane] : 0;
  int jmax = min(deg, 64);

  const float4* Xe4 = (const float4*)Xe;
  float4 acc = make_float4(0.f, 0.f, 0.f, 0.f);
  for (int jj = 0; jj < jmax; jj += 4) {   // jj uniform across the wave
    int j = jj + g;
    int e0 = __shfl(myidx, j & 63);        // convergent: all lanes active
    if (j < jmax) {
      float4 a = Xe4[(size_t)e0 * 16 + li];
      acc.x += a.x; acc.y += a.y; acc.z += a.z; acc.w += a.w;
    }
  }
  for (int j2 = 64 + g; j2 < deg; j2 += 4) {  // rare tail: direct loads
    int e0 = perm[start + j2];
    float4 a = Xe4[(size_t)e0 * 16 + li];
    acc.x += a.x; acc.y += a.y; acc.z += a.z; acc.w += a.w;
  }
  #pragma unroll
  for (int o = 16; o <= 32; o <<= 1) {
    acc.x += __shfl_xor(acc.x, o);
    acc.y += __shfl_xor(acc.y, o);
    acc.z += __shfl_xor(acc.z, o);
    acc.w += __shfl_xor(acc.w, o);
  }

  float dv = degv[node];
  acc.x *= dv; acc.y *= dv; acc.z *= dv; acc.w *= dv;

  float ss = acc.x * acc.x + acc.y * acc.y + acc.z * acc.z + acc.w * acc.w;
  #pragma unroll
  for (int o = 1; o <= 8; o <<= 1) ss += __shfl_xor(ss, o);
  float scale = ss > 0.0f ? 1.0f / sqrtf(ss) : 0.0f;
  acc.x *= scale; acc.y *= scale; acc.z *= scale; acc.w *= scale;

  // out[node] = xn @ W + b ; lane covers output cols 2*lane, 2*lane+1
  const float2* b2v = (const float2*)b;
  float2 accO = b2v[lane];
  #pragma unroll
  for (int kk = 0; kk < 16; ++kk) {
    float x0 = __shfl(acc.x, kk);
    float x1 = __shfl(acc.y, kk);
    float x2 = __shfl(acc.z, kk);
    float x3 = __shfl(acc.w, kk);
    const float2* Wr = (const float2*)&Ws[(4 * kk) * DOUT];
    float2 w0 = Wr[lane];
    float2 w1 = Wr[64 + lane];
    float2 w2 = Wr[128 + lane];
    float2 w3 = Wr[192 + lane];
    accO.x += x0 * w0.x + x1 * w1.x + x2 * w2.x + x3 * w3.x;
    accO.y += x0 * w0.y + x1 * w1.y + x2 * w2.y + x3 * w3.y;
  }
  ((float2*)out)[(size_t)node * 64 + lane] = accO;
}

extern "C" void kernel_launch(void* const* d_in, const int* in_sizes, int n_in,
                              void* d_out, int out_size, void* d_ws, size_t ws_size,
                              hipStream_t stream) {
  const float* X      = (const float*)d_in[0];
  const int*   vertex = (const int*)d_in[1];
  const int*   edges  = (const int*)d_in[2];
  const float* dege   = (const float*)d_in[3];
  const float* degv   = (const float*)d_in[4];
  const float* W      = (const float*)d_in[5];
  const float* b      = (const float*)d_in[6];
  float* out = (float*)d_out;

  int N = in_sizes[0] / DIN;   // 100000
  int E = in_sizes[1];         // 1000000
  int M = in_sizes[3];         // 200000

  int NCH = (E + CH - 1) / CH;           // 245
  int BKE = (M + 1023) >> BSHIFT;        // 196
  int BKV = (N + 1023) >> BSHIFT;        // 98
  int BK  = BKE + BKV;                   // 294

  // workspace layout
  float*    Xe   = (float*)d_ws;                           // M*64 f32 (51.2 MB)
  int*      off  = (int*)(Xe + (size_t)M * DIN);           // M+N
  int*      perm = off + (M + N);                          // 2E
  unsigned* temp = (unsigned*)(perm + 2 * (size_t)E);      // 2E packed (8 MB)
  int*      G    = (int*)(temp + 2 * (size_t)E);           // BK*NCH
  int*      rowTot = G + (size_t)BK * NCH;                 // BK
  int*      bucketBase = rowTot + BK;                      // BK+1

  p1_hist<<<NCH, 256, 0, stream>>>(vertex, edges, G, E, BKE, BK, NCH);
  p1b_rowscan<<<BK, 256, 0, stream>>>(G, rowTot, NCH);
  p1c_scan<<<1, 64, 0, stream>>>(rowTot, bucketBase, BK);
  p2_scatter<<<NCH, 256, 0, stream>>>(vertex, edges, G, bucketBase, temp, E, BKE, BK, NCH);
  p3_sort<<<BK, 256, 0, stream>>>(temp, bucketBase, off, perm, BKE, M, N);

  long long eWaveThreads = (long long)M * 64;
  int edgeBlocks = (int)((eWaveThreads + 255) / 256);
  k_edge<<<edgeBlocks, 256, 0, stream>>>(X, off, perm, dege, Xe, M);

  long long nWaveThreads = (long long)N * 64;
  int nodeBlocks = (int)((nWaveThreads + 511) / 512);
  k_node<<<nodeBlocks, 512, 0, stream>>>(Xe, off, perm, degv, W, b, out, N, M);
}

// Round 9
// 171.902 us; speedup vs baseline: 1.6425x; 1.6425x over previous
//
#include <hip/hip_runtime.h>

// UniGCNConv2: bucketed counting sort (packed keys, no global atomics) ->
// gather segment-mean into Xe (f32) -> gather segment-sum + degv + L2-norm
// into xn (bf16, unit rows) -> MFMA bf16 linear (xn @ W + b).
// Key change vs r8: linear moved OUT of k_node (its 128 LDS-pipe ops/node
// were the bottleneck); gather kernels process 4 segments/wave.
// N=100000, M=200000, E=1e6, D_IN=64, out 128.

#define DIN 64
#define DOUT 128
#define CH 4096
#define BSHIFT 10
#define PAYBITS 18
#define PAYMASK ((1u << PAYBITS) - 1u)

typedef float f32x4 __attribute__((ext_vector_type(4)));
typedef short bf16x8 __attribute__((ext_vector_type(8)));

__device__ __forceinline__ unsigned short f2b(float f) {
  unsigned u = __float_as_uint(f);
  u = u + 0x7fffu + ((u >> 16) & 1u);   // RNE
  return (unsigned short)(u >> 16);
}

// ---- P1: per-chunk coarse-bucket histogram (combined E and V tables) ----
__global__ __launch_bounds__(256) void p1_hist(
    const int* __restrict__ vertex, const int* __restrict__ edges,
    int* __restrict__ G, int E, int BKE, int BK, int NCH) {
  __shared__ int h[512];
  for (int i = threadIdx.x; i < BK; i += 256) h[i] = 0;
  __syncthreads();
  int c = blockIdx.x;
  int s = c * CH, e_ = min(E, s + CH);
  for (int i = s + threadIdx.x; i < e_; i += 256) {
    atomicAdd(&h[edges[i] >> BSHIFT], 1);
    atomicAdd(&h[BKE + (vertex[i] >> BSHIFT)], 1);
  }
  __syncthreads();
  for (int b = threadIdx.x; b < BK; b += 256) G[(size_t)b * NCH + c] = h[b];
}

// ---- P1b: exclusive scan of each bucket row across chunks ----
__global__ __launch_bounds__(256) void p1b_rowscan(
    int* __restrict__ G, int* __restrict__ rowTot, int NCH) {
  int b = blockIdx.x;
  int* row = G + (size_t)b * NCH;
  __shared__ int wsum[4];
  __shared__ int carry;
  if (threadIdx.x == 0) carry = 0;
  __syncthreads();
  for (int base = 0; base < NCH; base += 256) {
    int i = base + threadIdx.x;
    int v = (i < NCH) ? row[i] : 0;
    int lane = threadIdx.x & 63, wid = threadIdx.x >> 6;
    int inc = v;
    #pragma unroll
    for (int o = 1; o < 64; o <<= 1) {
      int t = __shfl_up(inc, o);
      if (lane >= o) inc += t;
    }
    if (lane == 63) wsum[wid] = inc;
    __syncthreads();
    int woff = carry;
    for (int w = 0; w < wid; ++w) woff += wsum[w];
    int excl = woff + inc - v;
    if (i < NCH) row[i] = excl;
    __syncthreads();
    if (threadIdx.x == 0) carry += wsum[0] + wsum[1] + wsum[2] + wsum[3];
    __syncthreads();
  }
  if (threadIdx.x == 0) rowTot[b] = carry;
}

// ---- P1c: bucket bases ----
__global__ void p1c_scan(const int* __restrict__ rowTot,
                         int* __restrict__ bucketBase, int BK) {
  if (threadIdx.x == 0 && blockIdx.x == 0) {
    int s = 0;
    for (int b = 0; b < BK; ++b) { bucketBase[b] = s; s += rowTot[b]; }
    bucketBase[BK] = s;
  }
}

// ---- P2: scatter packed (fine,payload) via LDS cursors ----
__global__ __launch_bounds__(256) void p2_scatter(
    const int* __restrict__ vertex, const int* __restrict__ edges,
    const int* __restrict__ G, const int* __restrict__ bucketBase,
    unsigned* __restrict__ temp, int E, int BKE, int BK, int NCH) {
  __shared__ int curs[512];
  int c = blockIdx.x;
  for (int b = threadIdx.x; b < BK; b += 256)
    curs[b] = bucketBase[b] + G[(size_t)b * NCH + c];
  __syncthreads();
  int s = c * CH, e_ = min(E, s + CH);
  for (int i = s + threadIdx.x; i < e_; i += 256) {
    int e = edges[i], v = vertex[i];
    int pE = atomicAdd(&curs[e >> BSHIFT], 1);
    temp[pE] = ((unsigned)(e & 1023) << PAYBITS) | (unsigned)v;
    int pV = atomicAdd(&curs[BKE + (v >> BSHIFT)], 1);
    temp[pV] = ((unsigned)(v & 1023) << PAYBITS) | (unsigned)e;
  }
}

// ---- P3: per-bucket fine counting sort -> off (inclusive ends) + perm ----
__global__ __launch_bounds__(256) void p3_sort(
    const unsigned* __restrict__ temp, const int* __restrict__ bucketBase,
    int* __restrict__ off, int* __restrict__ perm, int BKE, int M, int N) {
  __shared__ int hist[1024];
  __shared__ int pos[1024];
  __shared__ int wsum[4];
  int g = blockIdx.x;
  bool isE = g < BKE;
  int gg = isE ? g : g - BKE;
  int keyBase = gg << BSHIFT;
  int cap = isE ? M : N;
  int offBase = (isE ? 0 : M) + keyBase;
  int fineCount = min(1024, cap - keyBase);
  int pairBase = bucketBase[g], pairEnd = bucketBase[g + 1];
  int cnt = pairEnd - pairBase;

  for (int i = threadIdx.x; i < 1024; i += 256) hist[i] = 0;
  __syncthreads();
  for (int i = threadIdx.x; i < cnt; i += 256)
    atomicAdd(&hist[temp[pairBase + i] >> PAYBITS], 1);
  __syncthreads();

  int t4 = threadIdx.x * 4;
  int a0 = hist[t4], a1 = hist[t4 + 1], a2 = hist[t4 + 2], a3 = hist[t4 + 3];
  int tsum = a0 + a1 + a2 + a3;
  int lane = threadIdx.x & 63, wid = threadIdx.x >> 6;
  int inc = tsum;
  #pragma unroll
  for (int o = 1; o < 64; o <<= 1) {
    int t = __shfl_up(inc, o);
    if (lane >= o) inc += t;
  }
  if (lane == 63) wsum[wid] = inc;
  __syncthreads();
  int woff = 0;
  for (int w = 0; w < wid; ++w) woff += wsum[w];
  int excl = woff + inc - tsum;
  pos[t4] = excl; pos[t4 + 1] = excl + a0;
  pos[t4 + 2] = excl + a0 + a1; pos[t4 + 3] = excl + a0 + a1 + a2;
  __syncthreads();

  for (int f = threadIdx.x; f < fineCount; f += 256)
    off[offBase + f] = pairBase + pos[f] + hist[f];
  for (int f = threadIdx.x; f < 1024; f += 256) pos[f] += pairBase;
  __syncthreads();

  for (int i = threadIdx.x; i < cnt; i += 256) {
    unsigned p = temp[pairBase + i];
    int q = atomicAdd(&pos[p >> PAYBITS], 1);
    perm[q] = (int)(p & PAYMASK);
  }
}

// ---- compute passes ----

// 4 hyperedges per wave, one per 16-lane group; group's 16 lanes hold the
// full 64-f32 row (float4/lane). Convergent shfl (uniform wave loop bound).
__global__ __launch_bounds__(256) void k_edge(
    const float* __restrict__ X, const int* __restrict__ off,
    const int* __restrict__ perm, const float* __restrict__ dege,
    float* __restrict__ Xe, int M) {
  long long gid = (long long)blockIdx.x * 256 + threadIdx.x;
  int wv = (int)(gid >> 6);
  int lane = threadIdx.x & 63;
  int g = lane >> 4, li = lane & 15;
  int e = wv * 4 + g;
  bool valid = e < M;
  int start = 0, end = 0;
  if (valid) { start = e ? off[e - 1] : 0; end = off[e]; }
  int deg = end - start;
  int myidx = (valid && li < deg) ? perm[start + li] : 0;
  int jmax = min(deg, 16);
  int jw = jmax;
  jw = max(jw, __shfl_xor(jw, 16));
  jw = max(jw, __shfl_xor(jw, 32));
  const float4* X4 = (const float4*)X;
  float4 acc = make_float4(0.f, 0.f, 0.f, 0.f);
  #pragma unroll 4
  for (int j = 0; j < jw; ++j) {
    int v0 = __shfl(myidx, (g << 4) + j);   // all 64 lanes active
    if (j < jmax) {
      float4 a = X4[(size_t)v0 * 16 + li];
      acc.x += a.x; acc.y += a.y; acc.z += a.z; acc.w += a.w;
    }
  }
  for (int j = 16; j < deg; ++j) {          // rare tail (deg>16)
    int v0 = perm[start + j];
    float4 a = X4[(size_t)v0 * 16 + li];
    acc.x += a.x; acc.y += a.y; acc.z += a.z; acc.w += a.w;
  }
  if (valid) {
    float s = dege[e] / fmaxf((float)deg, 1.0f);
    float4 r = make_float4(acc.x * s, acc.y * s, acc.z * s, acc.w * s);
    ((float4*)Xe)[(size_t)e * 16 + li] = r;
  }
}

// 4 nodes per wave; gather Xe rows, degv scale, L2 normalize, write bf16 xn.
__global__ __launch_bounds__(256) void k_nodeagg(
    const float* __restrict__ Xe, const int* __restrict__ off,
    const int* __restrict__ perm, const float* __restrict__ degv,
    unsigned short* __restrict__ xn, int N, int M) {
  long long gid = (long long)blockIdx.x * 256 + threadIdx.x;
  int wv = (int)(gid >> 6);
  int lane = threadIdx.x & 63;
  int g = lane >> 4, li = lane & 15;
  int node = wv * 4 + g;
  bool valid = node < N;
  int start = 0, end = 0;
  if (valid) { start = off[M + node - 1]; end = off[M + node]; }  // node0: off[M-1]==E
  int deg = end - start;
  int myidx = (valid && li < deg) ? perm[start + li] : 0;
  int jmax = min(deg, 16);
  int jw = jmax;
  jw = max(jw, __shfl_xor(jw, 16));
  jw = max(jw, __shfl_xor(jw, 32));
  const float4* Xe4 = (const float4*)Xe;
  float4 acc = make_float4(0.f, 0.f, 0.f, 0.f);
  #pragma unroll 4
  for (int j = 0; j < jw; ++j) {
    int e0 = __shfl(myidx, (g << 4) + j);   // all 64 lanes active
    if (j < jmax) {
      float4 a = Xe4[(size_t)e0 * 16 + li];
      acc.x += a.x; acc.y += a.y; acc.z += a.z; acc.w += a.w;
    }
  }
  for (int j = 16; j < deg; ++j) {          // tail (deg>16), ~3% of nodes
    int e0 = perm[start + j];
    float4 a = Xe4[(size_t)e0 * 16 + li];
    acc.x += a.x; acc.y += a.y; acc.z += a.z; acc.w += a.w;
  }
  float dv = valid ? degv[node] : 0.f;
  acc.x *= dv; acc.y *= dv; acc.z *= dv; acc.w *= dv;
  float ss = acc.x * acc.x + acc.y * acc.y + acc.z * acc.z + acc.w * acc.w;
  #pragma unroll
  for (int o = 1; o <= 8; o <<= 1) ss += __shfl_xor(ss, o);  // within group
  float sc = ss > 0.0f ? 1.0f / sqrtf(ss) : 0.0f;
  if (valid) {
    ushort4 r;
    r.x = f2b(acc.x * sc); r.y = f2b(acc.y * sc);
    r.z = f2b(acc.z * sc); r.w = f2b(acc.w * sc);
    ((ushort4*)xn)[(size_t)node * 16 + li] = r;
  }
}

// out[N x 128] = xn(bf16) @ W + b via mfma_f32_16x16x32_bf16.
// A frag: row = lane&15, k = (lane>>4)*8 + j. B frag: col = lane&15, same k.
// C/D: col = lane&15, row = (lane>>4)*4 + reg  [m89-verified].
#define WPAD 72
__global__ __launch_bounds__(256) void k_linear(
    const unsigned short* __restrict__ xn, const float* __restrict__ W,
    const float* __restrict__ bias, float* __restrict__ out, int N) {
  __shared__ unsigned short Wt[DOUT * WPAD];  // [col][k], padded, 18.4 KB
  for (int i = threadIdx.x; i < DIN * DOUT; i += 256) {
    int k = i >> 7, c = i & 127;   // W[k][c]
    Wt[c * WPAD + k] = f2b(W[i]);
  }
  __syncthreads();
  int lane = threadIdx.x & 63;
  int wid = threadIdx.x >> 6;
  int r = lane & 15, h = lane >> 4;

  bf16x8 Bf[8][2];
  #pragma unroll
  for (int c = 0; c < 8; ++c) {
    #pragma unroll
    for (int ks = 0; ks < 2; ++ks) {
      int col = c * 16 + r;
      int k0 = ks * 32 + h * 8;
      Bf[c][ks] = *(const bf16x8*)&Wt[col * WPAD + k0];
    }
  }
  float bcol[8];
  #pragma unroll
  for (int c = 0; c < 8; ++c) bcol[c] = bias[c * 16 + r];

  int strips = (N + 15) >> 4;   // N=100000 -> 6250 exact
  for (int s = blockIdx.x * 4 + wid; s < strips; s += gridDim.x * 4) {
    int row0 = s << 4;
    const unsigned short* xrow = xn + (size_t)(row0 + r) * DIN;
    bf16x8 a0 = *(const bf16x8*)&xrow[h * 8];
    bf16x8 a1 = *(const bf16x8*)&xrow[32 + h * 8];
    #pragma unroll
    for (int c = 0; c < 8; ++c) {
      f32x4 acc = {bcol[c], bcol[c], bcol[c], bcol[c]};
      acc = __builtin_amdgcn_mfma_f32_16x16x32_bf16(a0, Bf[c][0], acc, 0, 0, 0);
      acc = __builtin_amdgcn_mfma_f32_16x16x32_bf16(a1, Bf[c][1], acc, 0, 0, 0);
      #pragma unroll
      for (int q = 0; q < 4; ++q)
        out[(size_t)(row0 + h * 4 + q) * DOUT + c * 16 + r] = acc[q];
    }
  }
}

extern "C" void kernel_launch(void* const* d_in, const int* in_sizes, int n_in,
                              void* d_out, int out_size, void* d_ws, size_t ws_size,
                              hipStream_t stream) {
  const float* X      = (const float*)d_in[0];
  const int*   vertex = (const int*)d_in[1];
  const int*   edges  = (const int*)d_in[2];
  const float* dege   = (const float*)d_in[3];
  const float* degv   = (const float*)d_in[4];
  const float* W      = (const float*)d_in[5];
  const float* b      = (const float*)d_in[6];
  float* out = (float*)d_out;

  int N = in_sizes[0] / DIN;   // 100000
  int E = in_sizes[1];         // 1000000
  int M = in_sizes[3];         // 200000

  int NCH = (E + CH - 1) / CH;           // 245
  int BKE = (M + 1023) >> BSHIFT;        // 196
  int BKV = (N + 1023) >> BSHIFT;        // 98
  int BK  = BKE + BKV;                   // 294

  // workspace layout; temp (dead after p3) aliases xn (written after p3)
  float* Xe   = (float*)d_ws;                               // M*64 f32 (51.2 MB)
  int*   off  = (int*)(Xe + (size_t)M * DIN);               // M+N
  int*   perm = off + (M + N);                              // 2E
  char*  R    = (char*)(perm + 2 * (size_t)E);
  unsigned*       temp = (unsigned*)R;                      // 2E u32 (8 MB)
  unsigned short* xn   = (unsigned short*)R;                // N*64 bf16 (12.8 MB)
  size_t rBytes = (size_t)2 * E * 4;
  size_t xBytes = (size_t)N * DIN * 2;
  char*  R2   = R + (rBytes > xBytes ? rBytes : xBytes);
  int*   G    = (int*)R2;                                   // BK*NCH
  int*   rowTot = G + (size_t)BK * NCH;                     // BK
  int*   bucketBase = rowTot + BK;                          // BK+1

  p1_hist<<<NCH, 256, 0, stream>>>(vertex, edges, G, E, BKE, BK, NCH);
  p1b_rowscan<<<BK, 256, 0, stream>>>(G, rowTot, NCH);
  p1c_scan<<<1, 64, 0, stream>>>(rowTot, bucketBase, BK);
  p2_scatter<<<NCH, 256, 0, stream>>>(vertex, edges, G, bucketBase, temp, E, BKE, BK, NCH);
  p3_sort<<<BK, 256, 0, stream>>>(temp, bucketBase, off, perm, BKE, M, N);

  int edgeBlocks = (M + 15) / 16;        // 4 edges/wave, 4 waves/block
  k_edge<<<edgeBlocks, 256, 0, stream>>>(X, off, perm, dege, Xe, M);

  int nodeBlocks = (N + 15) / 16;
  k_nodeagg<<<nodeBlocks, 256, 0, stream>>>(Xe, off, perm, degv, xn, N, M);

  k_linear<<<1024, 256, 0, stream>>>(xn, W, b, out, N);
}

// Round 10
// 159.585 us; speedup vs baseline: 1.7693x; 1.0772x over previous
//
#include <hip/hip_runtime.h>

// UniGCNConv2: bucketed counting sort (packed keys, no global atomics) ->
// X cast to bf16 -> gather segment-mean into Xe (bf16 storage, f32 accum) ->
// gather segment-sum + degv + L2-norm into xn (bf16 unit rows) ->
// MFMA bf16 linear (xn @ W + b, f32 out).
// N=100000, M=200000, E=1e6, D_IN=64, out 128.

#define DIN 64
#define DOUT 128
#define CH 4096
#define BSHIFT 10
#define PAYBITS 18
#define PAYMASK ((1u << PAYBITS) - 1u)

typedef float f32x4 __attribute__((ext_vector_type(4)));
typedef short bf16x8 __attribute__((ext_vector_type(8)));

__device__ __forceinline__ unsigned short f2b(float f) {
  unsigned u = __float_as_uint(f);
  u = u + 0x7fffu + ((u >> 16) & 1u);   // RNE
  return (unsigned short)(u >> 16);
}
__device__ __forceinline__ float b2f(unsigned s) {
  return __uint_as_float(s << 16);
}

// ---- P1: per-chunk coarse-bucket histogram (combined E and V tables) ----
__global__ __launch_bounds__(256) void p1_hist(
    const int* __restrict__ vertex, const int* __restrict__ edges,
    int* __restrict__ G, int E, int BKE, int BK, int NCH) {
  __shared__ int h[512];
  for (int i = threadIdx.x; i < BK; i += 256) h[i] = 0;
  __syncthreads();
  int c = blockIdx.x;
  int s = c * CH, e_ = min(E, s + CH);
  for (int i = s + threadIdx.x; i < e_; i += 256) {
    atomicAdd(&h[edges[i] >> BSHIFT], 1);
    atomicAdd(&h[BKE + (vertex[i] >> BSHIFT)], 1);
  }
  __syncthreads();
  for (int b = threadIdx.x; b < BK; b += 256) G[(size_t)b * NCH + c] = h[b];
}

// ---- P1b: exclusive scan of each bucket row across chunks ----
__global__ __launch_bounds__(256) void p1b_rowscan(
    int* __restrict__ G, int* __restrict__ rowTot, int NCH) {
  int b = blockIdx.x;
  int* row = G + (size_t)b * NCH;
  __shared__ int wsum[4];
  __shared__ int carry;
  if (threadIdx.x == 0) carry = 0;
  __syncthreads();
  for (int base = 0; base < NCH; base += 256) {
    int i = base + threadIdx.x;
    int v = (i < NCH) ? row[i] : 0;
    int lane = threadIdx.x & 63, wid = threadIdx.x >> 6;
    int inc = v;
    #pragma unroll
    for (int o = 1; o < 64; o <<= 1) {
      int t = __shfl_up(inc, o);
      if (lane >= o) inc += t;
    }
    if (lane == 63) wsum[wid] = inc;
    __syncthreads();
    int woff = carry;
    for (int w = 0; w < wid; ++w) woff += wsum[w];
    int excl = woff + inc - v;
    if (i < NCH) row[i] = excl;
    __syncthreads();
    if (threadIdx.x == 0) carry += wsum[0] + wsum[1] + wsum[2] + wsum[3];
    __syncthreads();
  }
  if (threadIdx.x == 0) rowTot[b] = carry;
}

// ---- P1c: bucket bases ----
__global__ void p1c_scan(const int* __restrict__ rowTot,
                         int* __restrict__ bucketBase, int BK) {
  if (threadIdx.x == 0 && blockIdx.x == 0) {
    int s = 0;
    for (int b = 0; b < BK; ++b) { bucketBase[b] = s; s += rowTot[b]; }
    bucketBase[BK] = s;
  }
}

// ---- P2: scatter packed (fine,payload) via LDS cursors ----
__global__ __launch_bounds__(256) void p2_scatter(
    const int* __restrict__ vertex, const int* __restrict__ edges,
    const int* __restrict__ G, const int* __restrict__ bucketBase,
    unsigned* __restrict__ temp, int E, int BKE, int BK, int NCH) {
  __shared__ int curs[512];
  int c = blockIdx.x;
  for (int b = threadIdx.x; b < BK; b += 256)
    curs[b] = bucketBase[b] + G[(size_t)b * NCH + c];
  __syncthreads();
  int s = c * CH, e_ = min(E, s + CH);
  for (int i = s + threadIdx.x; i < e_; i += 256) {
    int e = edges[i], v = vertex[i];
    int pE = atomicAdd(&curs[e >> BSHIFT], 1);
    temp[pE] = ((unsigned)(e & 1023) << PAYBITS) | (unsigned)v;
    int pV = atomicAdd(&curs[BKE + (v >> BSHIFT)], 1);
    temp[pV] = ((unsigned)(v & 1023) << PAYBITS) | (unsigned)e;
  }
}

// ---- P3: per-bucket fine counting sort -> off (inclusive ends) + perm ----
__global__ __launch_bounds__(256) void p3_sort(
    const unsigned* __restrict__ temp, const int* __restrict__ bucketBase,
    int* __restrict__ off, int* __restrict__ perm, int BKE, int M, int N) {
  __shared__ int hist[1024];
  __shared__ int pos[1024];
  __shared__ int wsum[4];
  int g = blockIdx.x;
  bool isE = g < BKE;
  int gg = isE ? g : g - BKE;
  int keyBase = gg << BSHIFT;
  int cap = isE ? M : N;
  int offBase = (isE ? 0 : M) + keyBase;
  int fineCount = min(1024, cap - keyBase);
  int pairBase = bucketBase[g], pairEnd = bucketBase[g + 1];
  int cnt = pairEnd - pairBase;

  for (int i = threadIdx.x; i < 1024; i += 256) hist[i] = 0;
  __syncthreads();
  for (int i = threadIdx.x; i < cnt; i += 256)
    atomicAdd(&hist[temp[pairBase + i] >> PAYBITS], 1);
  __syncthreads();

  int t4 = threadIdx.x * 4;
  int a0 = hist[t4], a1 = hist[t4 + 1], a2 = hist[t4 + 2], a3 = hist[t4 + 3];
  int tsum = a0 + a1 + a2 + a3;
  int lane = threadIdx.x & 63, wid = threadIdx.x >> 6;
  int inc = tsum;
  #pragma unroll
  for (int o = 1; o < 64; o <<= 1) {
    int t = __shfl_up(inc, o);
    if (lane >= o) inc += t;
  }
  if (lane == 63) wsum[wid] = inc;
  __syncthreads();
  int woff = 0;
  for (int w = 0; w < wid; ++w) woff += wsum[w];
  int excl = woff + inc - tsum;
  pos[t4] = excl; pos[t4 + 1] = excl + a0;
  pos[t4 + 2] = excl + a0 + a1; pos[t4 + 3] = excl + a0 + a1 + a2;
  __syncthreads();

  for (int f = threadIdx.x; f < fineCount; f += 256)
    off[offBase + f] = pairBase + pos[f] + hist[f];
  for (int f = threadIdx.x; f < 1024; f += 256) pos[f] += pairBase;
  __syncthreads();

  for (int i = threadIdx.x; i < cnt; i += 256) {
    unsigned p = temp[pairBase + i];
    int q = atomicAdd(&pos[p >> PAYBITS], 1);
    perm[q] = (int)(p & PAYMASK);
  }
}

// ---- compute passes ----

// X (f32) -> Xb (bf16). One float4 -> ushort4 per thread.
__global__ __launch_bounds__(256) void k_xcast(
    const float* __restrict__ X, unsigned short* __restrict__ Xb, int total4) {
  int i = blockIdx.x * 256 + threadIdx.x;
  if (i >= total4) return;
  float4 a = ((const float4*)X)[i];
  ushort4 r;
  r.x = f2b(a.x); r.y = f2b(a.y); r.z = f2b(a.z); r.w = f2b(a.w);
  ((ushort4*)Xb)[i] = r;
}

// 4 hyperedges per wave, one per 16-lane group; group's 16 lanes hold the
// full 64-bf16 row (uint2 = 4 bf16/lane). Convergent shfl; f32 accumulate;
// bf16 Xe write.
__global__ __launch_bounds__(256) void k_edge(
    const unsigned short* __restrict__ Xb, const int* __restrict__ off,
    const int* __restrict__ perm, const float* __restrict__ dege,
    unsigned short* __restrict__ Xe, int M) {
  long long gid = (long long)blockIdx.x * 256 + threadIdx.x;
  int wv = (int)(gid >> 6);
  int lane = threadIdx.x & 63;
  int g = lane >> 4, li = lane & 15;
  int e = wv * 4 + g;
  bool valid = e < M;
  int start = 0, end = 0;
  if (valid) { start = e ? off[e - 1] : 0; end = off[e]; }
  int deg = end - start;
  int myidx = (valid && li < deg) ? perm[start + li] : 0;
  int jmax = min(deg, 16);
  int jw = jmax;
  jw = max(jw, __shfl_xor(jw, 16));
  jw = max(jw, __shfl_xor(jw, 32));
  const uint2* X2 = (const uint2*)Xb;   // 16 uint2 per 64-elem row
  float4 acc = make_float4(0.f, 0.f, 0.f, 0.f);
  #pragma unroll 4
  for (int j = 0; j < jw; ++j) {
    int v0 = __shfl(myidx, (g << 4) + j);   // all 64 lanes active
    if (j < jmax) {
      uint2 a = X2[(size_t)v0 * 16 + li];
      acc.x += b2f(a.x & 0xffffu); acc.y += b2f(a.x >> 16);
      acc.z += b2f(a.y & 0xffffu); acc.w += b2f(a.y >> 16);
    }
  }
  for (int j = 16; j < deg; ++j) {          // rare tail (deg>16)
    int v0 = perm[start + j];
    uint2 a = X2[(size_t)v0 * 16 + li];
    acc.x += b2f(a.x & 0xffffu); acc.y += b2f(a.x >> 16);
    acc.z += b2f(a.y & 0xffffu); acc.w += b2f(a.y >> 16);
  }
  if (valid) {
    float s = dege[e] / fmaxf((float)deg, 1.0f);
    ushort4 r;
    r.x = f2b(acc.x * s); r.y = f2b(acc.y * s);
    r.z = f2b(acc.z * s); r.w = f2b(acc.w * s);
    ((ushort4*)Xe)[(size_t)e * 16 + li] = r;
  }
}

// 4 nodes per wave; gather bf16 Xe rows (f32 accum), degv scale, L2 normalize,
// write bf16 xn.
__global__ __launch_bounds__(256) void k_nodeagg(
    const unsigned short* __restrict__ Xe, const int* __restrict__ off,
    const int* __restrict__ perm, const float* __restrict__ degv,
    unsigned short* __restrict__ xn, int N, int M) {
  long long gid = (long long)blockIdx.x * 256 + threadIdx.x;
  int wv = (int)(gid >> 6);
  int lane = threadIdx.x & 63;
  int g = lane >> 4, li = lane & 15;
  int node = wv * 4 + g;
  bool valid = node < N;
  int start = 0, end = 0;
  if (valid) { start = off[M + node - 1]; end = off[M + node]; }  // node0: off[M-1]==E
  int deg = end - start;
  int myidx = (valid && li < deg) ? perm[start + li] : 0;
  int jmax = min(deg, 16);
  int jw = jmax;
  jw = max(jw, __shfl_xor(jw, 16));
  jw = max(jw, __shfl_xor(jw, 32));
  const uint2* Xe2 = (const uint2*)Xe;
  float4 acc = make_float4(0.f, 0.f, 0.f, 0.f);
  #pragma unroll 4
  for (int j = 0; j < jw; ++j) {
    int e0 = __shfl(myidx, (g << 4) + j);   // all 64 lanes active
    if (j < jmax) {
      uint2 a = Xe2[(size_t)e0 * 16 + li];
      acc.x += b2f(a.x & 0xffffu); acc.y += b2f(a.x >> 16);
      acc.z += b2f(a.y & 0xffffu); acc.w += b2f(a.y >> 16);
    }
  }
  for (int j = 16; j < deg; ++j) {          // tail (deg>16), ~3% of nodes
    int e0 = perm[start + j];
    uint2 a = Xe2[(size_t)e0 * 16 + li];
    acc.x += b2f(a.x & 0xffffu); acc.y += b2f(a.x >> 16);
    acc.z += b2f(a.y & 0xffffu); acc.w += b2f(a.y >> 16);
  }
  float dv = valid ? degv[node] : 0.f;
  acc.x *= dv; acc.y *= dv; acc.z *= dv; acc.w *= dv;
  float ss = acc.x * acc.x + acc.y * acc.y + acc.z * acc.z + acc.w * acc.w;
  #pragma unroll
  for (int o = 1; o <= 8; o <<= 1) ss += __shfl_xor(ss, o);  // within group
  float sc = ss > 0.0f ? 1.0f / sqrtf(ss) : 0.0f;
  if (valid) {
    ushort4 r;
    r.x = f2b(acc.x * sc); r.y = f2b(acc.y * sc);
    r.z = f2b(acc.z * sc); r.w = f2b(acc.w * sc);
    ((ushort4*)xn)[(size_t)node * 16 + li] = r;
  }
}

// out[N x 128] = xn(bf16) @ W + b via mfma_f32_16x16x32_bf16.
// A frag: row = lane&15, k = (lane>>4)*8 + j. B frag: col = lane&15, same k.
// C/D: col = lane&15, row = (lane>>4)*4 + reg  [m89-verified].
#define WPAD 72
__global__ __launch_bounds__(256) void k_linear(
    const unsigned short* __restrict__ xn, const float* __restrict__ W,
    const float* __restrict__ bias, float* __restrict__ out, int N) {
  __shared__ unsigned short Wt[DOUT * WPAD];  // [col][k], padded, 18.4 KB
  for (int i = threadIdx.x; i < DIN * DOUT; i += 256) {
    int k = i >> 7, c = i & 127;   // W[k][c]
    Wt[c * WPAD + k] = f2b(W[i]);
  }
  __syncthreads();
  int lane = threadIdx.x & 63;
  int wid = threadIdx.x >> 6;
  int r = lane & 15, h = lane >> 4;

  bf16x8 Bf[8][2];
  #pragma unroll
  for (int c = 0; c < 8; ++c) {
    #pragma unroll
    for (int ks = 0; ks < 2; ++ks) {
      int col = c * 16 + r;
      int k0 = ks * 32 + h * 8;
      Bf[c][ks] = *(const bf16x8*)&Wt[col * WPAD + k0];
    }
  }
  float bcol[8];
  #pragma unroll
  for (int c = 0; c < 8; ++c) bcol[c] = bias[c * 16 + r];

  int strips = (N + 15) >> 4;   // N=100000 -> 6250 exact
  for (int s = blockIdx.x * 4 + wid; s < strips; s += gridDim.x * 4) {
    int row0 = s << 4;
    const unsigned short* xrow = xn + (size_t)(row0 + r) * DIN;
    bf16x8 a0 = *(const bf16x8*)&xrow[h * 8];
    bf16x8 a1 = *(const bf16x8*)&xrow[32 + h * 8];
    #pragma unroll
    for (int c = 0; c < 8; ++c) {
      f32x4 acc = {bcol[c], bcol[c], bcol[c], bcol[c]};
      acc = __builtin_amdgcn_mfma_f32_16x16x32_bf16(a0, Bf[c][0], acc, 0, 0, 0);
      acc = __builtin_amdgcn_mfma_f32_16x16x32_bf16(a1, Bf[c][1], acc, 0, 0, 0);
      #pragma unroll
      for (int q = 0; q < 4; ++q)
        out[(size_t)(row0 + h * 4 + q) * DOUT + c * 16 + r] = acc[q];
    }
  }
}

extern "C" void kernel_launch(void* const* d_in, const int* in_sizes, int n_in,
                              void* d_out, int out_size, void* d_ws, size_t ws_size,
                              hipStream_t stream) {
  const float* X      = (const float*)d_in[0];
  const int*   vertex = (const int*)d_in[1];
  const int*   edges  = (const int*)d_in[2];
  const float* dege   = (const float*)d_in[3];
  const float* degv   = (const float*)d_in[4];
  const float* W      = (const float*)d_in[5];
  const float* b      = (const float*)d_in[6];
  float* out = (float*)d_out;

  int N = in_sizes[0] / DIN;   // 100000
  int E = in_sizes[1];         // 1000000
  int M = in_sizes[3];         // 200000

  int NCH = (E + CH - 1) / CH;           // 245
  int BKE = (M + 1023) >> BSHIFT;        // 196
  int BKV = (N + 1023) >> BSHIFT;        // 98
  int BK  = BKE + BKV;                   // 294

  // workspace layout; temp (dead after p3) aliases xn (written after p3)
  unsigned short* Xe = (unsigned short*)d_ws;               // M*64 bf16 (25.6 MB)
  unsigned short* Xb = Xe + (size_t)M * DIN;                // N*64 bf16 (12.8 MB)
  int*   off  = (int*)(Xb + (size_t)N * DIN);               // M+N
  int*   perm = off + (M + N);                              // 2E (8 MB)
  char*  R    = (char*)(perm + 2 * (size_t)E);
  unsigned*       temp = (unsigned*)R;                      // 2E u32 (8 MB)
  unsigned short* xn   = (unsigned short*)R;                // N*64 bf16 (12.8 MB)
  size_t rBytes = (size_t)2 * E * 4;
  size_t xBytes = (size_t)N * DIN * 2;
  char*  R2   = R + (rBytes > xBytes ? rBytes : xBytes);
  int*   G    = (int*)R2;                                   // BK*NCH
  int*   rowTot = G + (size_t)BK * NCH;                     // BK
  int*   bucketBase = rowTot + BK;                          // BK+1

  int xcast4 = N * DIN / 4;
  k_xcast<<<(xcast4 + 255) / 256, 256, 0, stream>>>(X, Xb, xcast4);

  p1_hist<<<NCH, 256, 0, stream>>>(vertex, edges, G, E, BKE, BK, NCH);
  p1b_rowscan<<<BK, 256, 0, stream>>>(G, rowTot, NCH);
  p1c_scan<<<1, 64, 0, stream>>>(rowTot, bucketBase, BK);
  p2_scatter<<<NCH, 256, 0, stream>>>(vertex, edges, G, bucketBase, temp, E, BKE, BK, NCH);
  p3_sort<<<BK, 256, 0, stream>>>(temp, bucketBase, off, perm, BKE, M, N);

  int edgeBlocks = (M + 15) / 16;        // 4 edges/wave, 4 waves/block
  k_edge<<<edgeBlocks, 256, 0, stream>>>(Xb, off, perm, dege, Xe, M);

  int nodeBlocks = (N + 15) / 16;
  k_nodeagg<<<nodeBlocks, 256, 0, stream>>>(Xe, off, perm, degv, xn, N, M);

  k_linear<<<1024, 256, 0, stream>>>(xn, W, b, out, N);
}

// Round 11
// 147.416 us; speedup vs baseline: 1.9154x; 1.0825x over previous
//
#include <hip/hip_runtime.h>

// UniGCNConv2: bucketed counting sort (packed keys, no global atomics) ->
// X cast bf16 (fused into p1) -> gather segment-mean Xe (bf16 store, f32
// accum) -> gather segment-sum + degv + L2-norm xn (bf16) -> MFMA linear.
// 7 launches. N=100000, M=200000, E=1e6, D_IN=64, out 128.

#define DIN 64
#define DOUT 128
#define CH 4096
#define BSHIFT 9          // fine range 512
#define FINE 512
#define PAYBITS 18
#define PAYMASK ((1u << PAYBITS) - 1u)
#define XB 256            // xcast helper blocks fused into p1

typedef float f32x4 __attribute__((ext_vector_type(4)));
typedef short bf16x8 __attribute__((ext_vector_type(8)));

__device__ __forceinline__ unsigned short f2b(float f) {
  unsigned u = __float_as_uint(f);
  u = u + 0x7fffu + ((u >> 16) & 1u);   // RNE
  return (unsigned short)(u >> 16);
}
__device__ __forceinline__ float b2f(unsigned s) {
  return __uint_as_float(s << 16);
}

// ---- P1: blocks [0,NCH): per-chunk coarse hist; blocks [NCH,NCH+XB): X->bf16.
// Block 0 also zeroes the p1b completion counter (replay-deterministic).
__global__ __launch_bounds__(256) void k_p1(
    const int* __restrict__ vertex, const int* __restrict__ edges,
    int* __restrict__ G, const float* __restrict__ X,
    unsigned short* __restrict__ Xb, int* __restrict__ done,
    int E, int BKE, int BK, int NCH, int total4) {
  if (blockIdx.x == 0 && threadIdx.x == 0) *done = 0;
  if (blockIdx.x >= (unsigned)NCH) {  // xcast role
    int xb = blockIdx.x - NCH;
    for (int i = xb * 256 + threadIdx.x; i < total4; i += XB * 256) {
      float4 a = ((const float4*)X)[i];
      ushort4 r;
      r.x = f2b(a.x); r.y = f2b(a.y); r.z = f2b(a.z); r.w = f2b(a.w);
      ((ushort4*)Xb)[i] = r;
    }
    return;
  }
  __shared__ int h[1024];
  for (int i = threadIdx.x; i < BK; i += 256) h[i] = 0;
  __syncthreads();
  int c = blockIdx.x;
  int s = c * CH, e_ = min(E, s + CH);
  for (int i = s + threadIdx.x; i < e_; i += 256) {
    atomicAdd(&h[edges[i] >> BSHIFT], 1);
    atomicAdd(&h[BKE + (vertex[i] >> BSHIFT)], 1);
  }
  __syncthreads();
  for (int b = threadIdx.x; b < BK; b += 256) G[(size_t)b * NCH + c] = h[b];
}

// ---- P1b: per-bucket row scan across chunks; LAST block also scans bucket
// totals into bucketBase (replaces p1c).
__global__ __launch_bounds__(256) void k_p1b(
    int* __restrict__ G, int* __restrict__ rowTot, int* __restrict__ bucketBase,
    int* __restrict__ done, int NCH, int BK) {
  int b = blockIdx.x;
  int* row = G + (size_t)b * NCH;
  __shared__ int wsum[4];
  __shared__ int carry;
  __shared__ bool amLast;
  if (threadIdx.x == 0) carry = 0;
  __syncthreads();
  for (int base = 0; base < NCH; base += 256) {
    int i = base + threadIdx.x;
    int v = (i < NCH) ? row[i] : 0;
    int lane = threadIdx.x & 63, wid = threadIdx.x >> 6;
    int inc = v;
    #pragma unroll
    for (int o = 1; o < 64; o <<= 1) {
      int t = __shfl_up(inc, o);
      if (lane >= o) inc += t;
    }
    if (lane == 63) wsum[wid] = inc;
    __syncthreads();
    int woff = carry;
    for (int w = 0; w < wid; ++w) woff += wsum[w];
    int excl = woff + inc - v;
    if (i < NCH) row[i] = excl;
    __syncthreads();
    if (threadIdx.x == 0) carry += wsum[0] + wsum[1] + wsum[2] + wsum[3];
    __syncthreads();
  }
  if (threadIdx.x == 0) {
    rowTot[b] = carry;
    __threadfence();
    amLast = (atomicAdd(done, 1) == gridDim.x - 1);
  }
  __syncthreads();
  if (!amLast) return;

  // final scan of rowTot[0..BK) -> bucketBase (exclusive) + sentinel
  if (threadIdx.x == 0) carry = 0;
  __syncthreads();
  for (int base = 0; base < BK; base += 256) {
    int i = base + threadIdx.x;
    int v = (i < BK) ? atomicAdd(&rowTot[i], 0) : 0;  // device-fresh read
    int lane = threadIdx.x & 63, wid = threadIdx.x >> 6;
    int inc = v;
    #pragma unroll
    for (int o = 1; o < 64; o <<= 1) {
      int t = __shfl_up(inc, o);
      if (lane >= o) inc += t;
    }
    if (lane == 63) wsum[wid] = inc;
    __syncthreads();
    int woff = carry;
    for (int w = 0; w < wid; ++w) woff += wsum[w];
    int excl = woff + inc - v;
    if (i < BK) bucketBase[i] = excl;
    __syncthreads();
    if (threadIdx.x == 0) carry += wsum[0] + wsum[1] + wsum[2] + wsum[3];
    __syncthreads();
  }
  if (threadIdx.x == 0) bucketBase[BK] = carry;
}

// ---- P2: scatter packed (fine,payload) via LDS cursors ----
__global__ __launch_bounds__(256) void p2_scatter(
    const int* __restrict__ vertex, const int* __restrict__ edges,
    const int* __restrict__ G, const int* __restrict__ bucketBase,
    unsigned* __restrict__ temp, int E, int BKE, int BK, int NCH) {
  __shared__ int curs[1024];
  int c = blockIdx.x;
  for (int b = threadIdx.x; b < BK; b += 256)
    curs[b] = bucketBase[b] + G[(size_t)b * NCH + c];
  __syncthreads();
  int s = c * CH, e_ = min(E, s + CH);
  for (int i = s + threadIdx.x; i < e_; i += 256) {
    int e = edges[i], v = vertex[i];
    int pE = atomicAdd(&curs[e >> BSHIFT], 1);
    temp[pE] = ((unsigned)(e & (FINE - 1)) << PAYBITS) | (unsigned)v;
    int pV = atomicAdd(&curs[BKE + (v >> BSHIFT)], 1);
    temp[pV] = ((unsigned)(v & (FINE - 1)) << PAYBITS) | (unsigned)e;
  }
}

// ---- P3: per-bucket fine counting sort -> off (inclusive ends) + perm ----
__global__ __launch_bounds__(256) void p3_sort(
    const unsigned* __restrict__ temp, const int* __restrict__ bucketBase,
    int* __restrict__ off, int* __restrict__ perm, int BKE, int M, int N) {
  __shared__ int hist[FINE];
  __shared__ int pos[FINE];
  __shared__ int wsum[4];
  int g = blockIdx.x;
  bool isE = g < BKE;
  int gg = isE ? g : g - BKE;
  int keyBase = gg << BSHIFT;
  int cap = isE ? M : N;
  int offBase = (isE ? 0 : M) + keyBase;
  int fineCount = min(FINE, cap - keyBase);
  int pairBase = bucketBase[g], pairEnd = bucketBase[g + 1];
  int cnt = pairEnd - pairBase;

  for (int i = threadIdx.x; i < FINE; i += 256) hist[i] = 0;
  __syncthreads();
  for (int i = threadIdx.x; i < cnt; i += 256)
    atomicAdd(&hist[temp[pairBase + i] >> PAYBITS], 1);
  __syncthreads();

  int t2 = threadIdx.x * 2;
  int a0 = hist[t2], a1 = hist[t2 + 1];
  int tsum = a0 + a1;
  int lane = threadIdx.x & 63, wid = threadIdx.x >> 6;
  int inc = tsum;
  #pragma unroll
  for (int o = 1; o < 64; o <<= 1) {
    int t = __shfl_up(inc, o);
    if (lane >= o) inc += t;
  }
  if (lane == 63) wsum[wid] = inc;
  __syncthreads();
  int woff = 0;
  for (int w = 0; w < wid; ++w) woff += wsum[w];
  int excl = woff + inc - tsum;
  pos[t2] = excl; pos[t2 + 1] = excl + a0;
  __syncthreads();

  for (int f = threadIdx.x; f < fineCount; f += 256)
    off[offBase + f] = pairBase + pos[f] + hist[f];
  for (int f = threadIdx.x; f < FINE; f += 256) pos[f] += pairBase;
  __syncthreads();

  for (int i = threadIdx.x; i < cnt; i += 256) {
    unsigned p = temp[pairBase + i];
    int q = atomicAdd(&pos[p >> PAYBITS], 1);
    perm[q] = (int)(p & PAYMASK);
  }
}

// ---- compute passes (unchanged numerics from round 10, absmax 3.9e-3) ----

// 4 hyperedges per wave; 16 lanes hold one 64-bf16 row (uint2/lane).
__global__ __launch_bounds__(256) void k_edge(
    const unsigned short* __restrict__ Xb, const int* __restrict__ off,
    const int* __restrict__ perm, const float* __restrict__ dege,
    unsigned short* __restrict__ Xe, int M) {
  long long gid = (long long)blockIdx.x * 256 + threadIdx.x;
  int wv = (int)(gid >> 6);
  int lane = threadIdx.x & 63;
  int g = lane >> 4, li = lane & 15;
  int e = wv * 4 + g;
  bool valid = e < M;
  int start = 0, end = 0;
  if (valid) { start = e ? off[e - 1] : 0; end = off[e]; }
  int deg = end - start;
  int myidx = (valid && li < deg) ? perm[start + li] : 0;
  int jmax = min(deg, 16);
  int jw = jmax;
  jw = max(jw, __shfl_xor(jw, 16));
  jw = max(jw, __shfl_xor(jw, 32));
  const uint2* X2 = (const uint2*)Xb;
  float4 acc = make_float4(0.f, 0.f, 0.f, 0.f);
  #pragma unroll 4
  for (int j = 0; j < jw; ++j) {
    int v0 = __shfl(myidx, (g << 4) + j);   // all 64 lanes active
    if (j < jmax) {
      uint2 a = X2[(size_t)v0 * 16 + li];
      acc.x += b2f(a.x & 0xffffu); acc.y += b2f(a.x >> 16);
      acc.z += b2f(a.y & 0xffffu); acc.w += b2f(a.y >> 16);
    }
  }
  for (int j = 16; j < deg; ++j) {          // rare tail
    int v0 = perm[start + j];
    uint2 a = X2[(size_t)v0 * 16 + li];
    acc.x += b2f(a.x & 0xffffu); acc.y += b2f(a.x >> 16);
    acc.z += b2f(a.y & 0xffffu); acc.w += b2f(a.y >> 16);
  }
  if (valid) {
    float s = dege[e] / fmaxf((float)deg, 1.0f);
    ushort4 r;
    r.x = f2b(acc.x * s); r.y = f2b(acc.y * s);
    r.z = f2b(acc.z * s); r.w = f2b(acc.w * s);
    ((ushort4*)Xe)[(size_t)e * 16 + li] = r;
  }
}

// 4 nodes per wave; gather bf16 Xe rows, degv scale, L2 normalize, bf16 xn.
__global__ __launch_bounds__(256) void k_nodeagg(
    const unsigned short* __restrict__ Xe, const int* __restrict__ off,
    const int* __restrict__ perm, const float* __restrict__ degv,
    unsigned short* __restrict__ xn, int N, int M) {
  long long gid = (long long)blockIdx.x * 256 + threadIdx.x;
  int wv = (int)(gid >> 6);
  int lane = threadIdx.x & 63;
  int g = lane >> 4, li = lane & 15;
  int node = wv * 4 + g;
  bool valid = node < N;
  int start = 0, end = 0;
  if (valid) { start = off[M + node - 1]; end = off[M + node]; }
  int deg = end - start;
  int myidx = (valid && li < deg) ? perm[start + li] : 0;
  int jmax = min(deg, 16);
  int jw = jmax;
  jw = max(jw, __shfl_xor(jw, 16));
  jw = max(jw, __shfl_xor(jw, 32));
  const uint2* Xe2 = (const uint2*)Xe;
  float4 acc = make_float4(0.f, 0.f, 0.f, 0.f);
  #pragma unroll 4
  for (int j = 0; j < jw; ++j) {
    int e0 = __shfl(myidx, (g << 4) + j);
    if (j < jmax) {
      uint2 a = Xe2[(size_t)e0 * 16 + li];
      acc.x += b2f(a.x & 0xffffu); acc.y += b2f(a.x >> 16);
      acc.z += b2f(a.y & 0xffffu); acc.w += b2f(a.y >> 16);
    }
  }
  for (int j = 16; j < deg; ++j) {
    int e0 = perm[start + j];
    uint2 a = Xe2[(size_t)e0 * 16 + li];
    acc.x += b2f(a.x & 0xffffu); acc.y += b2f(a.x >> 16);
    acc.z += b2f(a.y & 0xffffu); acc.w += b2f(a.y >> 16);
  }
  float dv = valid ? degv[node] : 0.f;
  acc.x *= dv; acc.y *= dv; acc.z *= dv; acc.w *= dv;
  float ss = acc.x * acc.x + acc.y * acc.y + acc.z * acc.z + acc.w * acc.w;
  #pragma unroll
  for (int o = 1; o <= 8; o <<= 1) ss += __shfl_xor(ss, o);
  float sc = ss > 0.0f ? 1.0f / sqrtf(ss) : 0.0f;
  if (valid) {
    ushort4 r;
    r.x = f2b(acc.x * sc); r.y = f2b(acc.y * sc);
    r.z = f2b(acc.z * sc); r.w = f2b(acc.w * sc);
    ((ushort4*)xn)[(size_t)node * 16 + li] = r;
  }
}

// out[N x 128] = xn(bf16) @ W + b via mfma_f32_16x16x32_bf16.
#define WPAD 72
__global__ __launch_bounds__(256) void k_linear(
    const unsigned short* __restrict__ xn, const float* __restrict__ W,
    const float* __restrict__ bias, float* __restrict__ out, int N) {
  __shared__ unsigned short Wt[DOUT * WPAD];
  for (int i = threadIdx.x; i < DIN * DOUT; i += 256) {
    int k = i >> 7, c = i & 127;   // W[k][c]
    Wt[c * WPAD + k] = f2b(W[i]);
  }
  __syncthreads();
  int lane = threadIdx.x & 63;
  int wid = threadIdx.x >> 6;
  int r = lane & 15, h = lane >> 4;

  bf16x8 Bf[8][2];
  #pragma unroll
  for (int c = 0; c < 8; ++c) {
    #pragma unroll
    for (int ks = 0; ks < 2; ++ks) {
      int col = c * 16 + r;
      int k0 = ks * 32 + h * 8;
      Bf[c][ks] = *(const bf16x8*)&Wt[col * WPAD + k0];
    }
  }
  float bcol[8];
  #pragma unroll
  for (int c = 0; c < 8; ++c) bcol[c] = bias[c * 16 + r];

  int strips = (N + 15) >> 4;
  for (int s = blockIdx.x * 4 + wid; s < strips; s += gridDim.x * 4) {
    int row0 = s << 4;
    const unsigned short* xrow = xn + (size_t)(row0 + r) * DIN;
    bf16x8 a0 = *(const bf16x8*)&xrow[h * 8];
    bf16x8 a1 = *(const bf16x8*)&xrow[32 + h * 8];
    #pragma unroll
    for (int c = 0; c < 8; ++c) {
      f32x4 acc = {bcol[c], bcol[c], bcol[c], bcol[c]};
      acc = __builtin_amdgcn_mfma_f32_16x16x32_bf16(a0, Bf[c][0], acc, 0, 0, 0);
      acc = __builtin_amdgcn_mfma_f32_16x16x32_bf16(a1, Bf[c][1], acc, 0, 0, 0);
      #pragma unroll
      for (int q = 0; q < 4; ++q)
        out[(size_t)(row0 + h * 4 + q) * DOUT + c * 16 + r] = acc[q];
    }
  }
}

extern "C" void kernel_launch(void* const* d_in, const int* in_sizes, int n_in,
                              void* d_out, int out_size, void* d_ws, size_t ws_size,
                              hipStream_t stream) {
  const float* X      = (const float*)d_in[0];
  const int*   vertex = (const int*)d_in[1];
  const int*   edges  = (const int*)d_in[2];
  const float* dege   = (const float*)d_in[3];
  const float* degv   = (const float*)d_in[4];
  const float* W      = (const float*)d_in[5];
  const float* b      = (const float*)d_in[6];
  float* out = (float*)d_out;

  int N = in_sizes[0] / DIN;   // 100000
  int E = in_sizes[1];         // 1000000
  int M = in_sizes[3];         // 200000

  int NCH = (E + CH - 1) / CH;                 // 245
  int BKE = (M + FINE - 1) >> BSHIFT;          // 391
  int BKV = (N + FINE - 1) >> BSHIFT;          // 196
  int BK  = BKE + BKV;                         // 587

  // workspace layout; temp (dead after p3) aliases xn (written after p3)
  unsigned short* Xe = (unsigned short*)d_ws;               // M*64 bf16 (25.6 MB)
  unsigned short* Xb = Xe + (size_t)M * DIN;                // N*64 bf16 (12.8 MB)
  int*   off  = (int*)(Xb + (size_t)N * DIN);               // M+N
  int*   perm = off + (M + N);                              // 2E (8 MB)
  char*  R    = (char*)(perm + 2 * (size_t)E);
  unsigned*       temp = (unsigned*)R;                      // 2E u32 (8 MB)
  unsigned short* xn   = (unsigned short*)R;                // N*64 bf16 (12.8 MB)
  size_t rBytes = (size_t)2 * E * 4;
  size_t xBytes = (size_t)N * DIN * 2;
  char*  R2   = R + (rBytes > xBytes ? rBytes : xBytes);
  int*   G    = (int*)R2;                                   // BK*NCH (575 KB)
  int*   rowTot = G + (size_t)BK * NCH;                     // BK
  int*   bucketBase = rowTot + BK;                          // BK+1
  int*   done = bucketBase + BK + 1;                        // 1

  int total4 = N * DIN / 4;
  k_p1<<<NCH + XB, 256, 0, stream>>>(vertex, edges, G, X, Xb, done,
                                     E, BKE, BK, NCH, total4);
  k_p1b<<<BK, 256, 0, stream>>>(G, rowTot, bucketBase, done, NCH, BK);
  p2_scatter<<<NCH, 256, 0, stream>>>(vertex, edges, G, bucketBase, temp,
                                      E, BKE, BK, NCH);
  p3_sort<<<BK, 256, 0, stream>>>(temp, bucketBase, off, perm, BKE, M, N);

  int edgeBlocks = (M + 15) / 16;
  k_edge<<<edgeBlocks, 256, 0, stream>>>(Xb, off, perm, dege, Xe, M);

  int nodeBlocks = (N + 15) / 16;
  k_nodeagg<<<nodeBlocks, 256, 0, stream>>>(Xe, off, perm, degv, xn, N, M);

  int strips = (N + 15) >> 4;
  int linBlocks = (strips + 3) / 4;          // one strip per wave
  k_linear<<<linBlocks, 256, 0, stream>>>(xn, W, b, out, N);
}

// Round 12
// 138.639 us; speedup vs baseline: 2.0366x; 1.0633x over previous
//
#include <hip/hip_runtime.h>

// UniGCNConv2: bucketed counting sort (packed keys, no global atomics) ->
// X cast bf16 + W transpose-cast (fused into p1) -> gather segment-mean Xe
// (bf16 store, f32 accum, 8 edges/wave) -> fused gather+degv+L2norm+MFMA
// linear (16-node strip per block, LDS-staged A). 6 launches.
// N=100000, M=200000, E=1e6, D_IN=64, out 128.

#define DIN 64
#define DOUT 128
#define CH 4096
#define BSHIFT 9          // fine range 512
#define FINE 512
#define PAYBITS 18
#define PAYMASK ((1u << PAYBITS) - 1u)
#define XB 256            // xcast helper blocks fused into p1

typedef float f32x4 __attribute__((ext_vector_type(4)));
typedef short bf16x8 __attribute__((ext_vector_type(8)));

__device__ __forceinline__ unsigned short f2b(float f) {
  unsigned u = __float_as_uint(f);
  u = u + 0x7fffu + ((u >> 16) & 1u);   // RNE
  return (unsigned short)(u >> 16);
}
__device__ __forceinline__ float b2f(unsigned s) {
  return __uint_as_float(s << 16);
}

// ---- P1: blocks [0,NCH): coarse hist (int4 reads); [NCH,NCH+XB): X->bf16;
// block NCH+XB: W -> Wbf transposed bf16. Block 0 zeroes the done counter.
__global__ __launch_bounds__(256) void k_p1(
    const int* __restrict__ vertex, const int* __restrict__ edges,
    int* __restrict__ G, const float* __restrict__ X,
    unsigned short* __restrict__ Xb, const float* __restrict__ W,
    unsigned short* __restrict__ Wbf, int* __restrict__ done,
    int E, int BKE, int BK, int NCH, int total4) {
  if (blockIdx.x == 0 && threadIdx.x == 0) *done = 0;
  if (blockIdx.x >= (unsigned)(NCH + XB)) {  // W transpose-cast role
    for (int i = threadIdx.x; i < DIN * DOUT; i += 256) {
      int k = i >> 7, c = i & 127;           // W[k][c]
      Wbf[c * DIN + k] = f2b(W[i]);
    }
    return;
  }
  if (blockIdx.x >= (unsigned)NCH) {  // xcast role
    int xb = blockIdx.x - NCH;
    for (int i = xb * 256 + threadIdx.x; i < total4; i += XB * 256) {
      float4 a = ((const float4*)X)[i];
      ushort4 r;
      r.x = f2b(a.x); r.y = f2b(a.y); r.z = f2b(a.z); r.w = f2b(a.w);
      ((ushort4*)Xb)[i] = r;
    }
    return;
  }
  __shared__ int h[1024];
  for (int i = threadIdx.x; i < BK; i += 256) h[i] = 0;
  __syncthreads();
  int c = blockIdx.x;
  int s = c * CH, e_ = min(E, s + CH);
  int n4 = (e_ - s) >> 2;
  const int4* ep = (const int4*)(edges + s);
  const int4* vp = (const int4*)(vertex + s);
  for (int i = threadIdx.x; i < n4; i += 256) {
    int4 ee = ep[i], vv = vp[i];
    atomicAdd(&h[ee.x >> BSHIFT], 1); atomicAdd(&h[ee.y >> BSHIFT], 1);
    atomicAdd(&h[ee.z >> BSHIFT], 1); atomicAdd(&h[ee.w >> BSHIFT], 1);
    atomicAdd(&h[BKE + (vv.x >> BSHIFT)], 1); atomicAdd(&h[BKE + (vv.y >> BSHIFT)], 1);
    atomicAdd(&h[BKE + (vv.z >> BSHIFT)], 1); atomicAdd(&h[BKE + (vv.w >> BSHIFT)], 1);
  }
  for (int i = s + (n4 << 2) + threadIdx.x; i < e_; i += 256) {
    atomicAdd(&h[edges[i] >> BSHIFT], 1);
    atomicAdd(&h[BKE + (vertex[i] >> BSHIFT)], 1);
  }
  __syncthreads();
  for (int b = threadIdx.x; b < BK; b += 256) G[(size_t)b * NCH + c] = h[b];
}

// ---- P1b: per-bucket row scan across chunks; last block scans bucket totals.
__global__ __launch_bounds__(256) void k_p1b(
    int* __restrict__ G, int* __restrict__ rowTot, int* __restrict__ bucketBase,
    int* __restrict__ done, int NCH, int BK) {
  int b = blockIdx.x;
  int* row = G + (size_t)b * NCH;
  __shared__ int wsum[4];
  __shared__ int carry;
  __shared__ bool amLast;
  if (threadIdx.x == 0) carry = 0;
  __syncthreads();
  for (int base = 0; base < NCH; base += 256) {
    int i = base + threadIdx.x;
    int v = (i < NCH) ? row[i] : 0;
    int lane = threadIdx.x & 63, wid = threadIdx.x >> 6;
    int inc = v;
    #pragma unroll
    for (int o = 1; o < 64; o <<= 1) {
      int t = __shfl_up(inc, o);
      if (lane >= o) inc += t;
    }
    if (lane == 63) wsum[wid] = inc;
    __syncthreads();
    int woff = carry;
    for (int w = 0; w < wid; ++w) woff += wsum[w];
    int excl = woff + inc - v;
    if (i < NCH) row[i] = excl;
    __syncthreads();
    if (threadIdx.x == 0) carry += wsum[0] + wsum[1] + wsum[2] + wsum[3];
    __syncthreads();
  }
  if (threadIdx.x == 0) {
    rowTot[b] = carry;
    __threadfence();
    amLast = (atomicAdd(done, 1) == gridDim.x - 1);
  }
  __syncthreads();
  if (!amLast) return;

  if (threadIdx.x == 0) carry = 0;
  __syncthreads();
  for (int base = 0; base < BK; base += 256) {
    int i = base + threadIdx.x;
    int v = (i < BK) ? atomicAdd(&rowTot[i], 0) : 0;  // device-fresh read
    int lane = threadIdx.x & 63, wid = threadIdx.x >> 6;
    int inc = v;
    #pragma unroll
    for (int o = 1; o < 64; o <<= 1) {
      int t = __shfl_up(inc, o);
      if (lane >= o) inc += t;
    }
    if (lane == 63) wsum[wid] = inc;
    __syncthreads();
    int woff = carry;
    for (int w = 0; w < wid; ++w) woff += wsum[w];
    int excl = woff + inc - v;
    if (i < BK) bucketBase[i] = excl;
    __syncthreads();
    if (threadIdx.x == 0) carry += wsum[0] + wsum[1] + wsum[2] + wsum[3];
    __syncthreads();
  }
  if (threadIdx.x == 0) bucketBase[BK] = carry;
}

// ---- P2: scatter packed (fine,payload) via LDS cursors ----
__global__ __launch_bounds__(256) void p2_scatter(
    const int* __restrict__ vertex, const int* __restrict__ edges,
    const int* __restrict__ G, const int* __restrict__ bucketBase,
    unsigned* __restrict__ temp, int E, int BKE, int BK, int NCH) {
  __shared__ int curs[1024];
  int c = blockIdx.x;
  for (int b = threadIdx.x; b < BK; b += 256)
    curs[b] = bucketBase[b] + G[(size_t)b * NCH + c];
  __syncthreads();
  int s = c * CH, e_ = min(E, s + CH);
  for (int i = s + threadIdx.x; i < e_; i += 256) {
    int e = edges[i], v = vertex[i];
    int pE = atomicAdd(&curs[e >> BSHIFT], 1);
    temp[pE] = ((unsigned)(e & (FINE - 1)) << PAYBITS) | (unsigned)v;
    int pV = atomicAdd(&curs[BKE + (v >> BSHIFT)], 1);
    temp[pV] = ((unsigned)(v & (FINE - 1)) << PAYBITS) | (unsigned)e;
  }
}

// ---- P3: per-bucket fine counting sort -> off (inclusive ends) + perm ----
__global__ __launch_bounds__(256) void p3_sort(
    const unsigned* __restrict__ temp, const int* __restrict__ bucketBase,
    int* __restrict__ off, int* __restrict__ perm, int BKE, int M, int N) {
  __shared__ int hist[FINE];
  __shared__ int pos[FINE];
  __shared__ int wsum[4];
  int g = blockIdx.x;
  bool isE = g < BKE;
  int gg = isE ? g : g - BKE;
  int keyBase = gg << BSHIFT;
  int cap = isE ? M : N;
  int offBase = (isE ? 0 : M) + keyBase;
  int fineCount = min(FINE, cap - keyBase);
  int pairBase = bucketBase[g], pairEnd = bucketBase[g + 1];
  int cnt = pairEnd - pairBase;

  for (int i = threadIdx.x; i < FINE; i += 256) hist[i] = 0;
  __syncthreads();
  for (int i = threadIdx.x; i < cnt; i += 256)
    atomicAdd(&hist[temp[pairBase + i] >> PAYBITS], 1);
  __syncthreads();

  int t2 = threadIdx.x * 2;
  int a0 = hist[t2], a1 = hist[t2 + 1];
  int tsum = a0 + a1;
  int lane = threadIdx.x & 63, wid = threadIdx.x >> 6;
  int inc = tsum;
  #pragma unroll
  for (int o = 1; o < 64; o <<= 1) {
    int t = __shfl_up(inc, o);
    if (lane >= o) inc += t;
  }
  if (lane == 63) wsum[wid] = inc;
  __syncthreads();
  int woff = 0;
  for (int w = 0; w < wid; ++w) woff += wsum[w];
  int excl = woff + inc - tsum;
  pos[t2] = excl; pos[t2 + 1] = excl + a0;
  __syncthreads();

  for (int f = threadIdx.x; f < fineCount; f += 256)
    off[offBase + f] = pairBase + pos[f] + hist[f];
  for (int f = threadIdx.x; f < FINE; f += 256) pos[f] += pairBase;
  __syncthreads();

  for (int i = threadIdx.x; i < cnt; i += 256) {
    unsigned p = temp[pairBase + i];
    int q = atomicAdd(&pos[p >> PAYBITS], 1);
    perm[q] = (int)(p & PAYMASK);
  }
}

// ---- compute passes ----

// 8 hyperedges per wave, one per 8-lane group; 8 lanes × uint4 = 128B row.
__global__ __launch_bounds__(256) void k_edge(
    const unsigned short* __restrict__ Xb, const int* __restrict__ off,
    const int* __restrict__ perm, const float* __restrict__ dege,
    unsigned short* __restrict__ Xe, int M) {
  long long gid = (long long)blockIdx.x * 256 + threadIdx.x;
  int wv = (int)(gid >> 6);
  int lane = threadIdx.x & 63;
  int g = lane >> 3, li = lane & 7;     // 8 groups of 8 lanes
  int e = wv * 8 + g;
  bool valid = e < M;
  int start = 0, end = 0;
  if (valid) { start = e ? off[e - 1] : 0; end = off[e]; }
  int deg = end - start;
  int myidx = (valid && li < deg) ? perm[start + li] : 0;
  int jmax = min(deg, 8);
  int jw = jmax;
  jw = max(jw, __shfl_xor(jw, 8));
  jw = max(jw, __shfl_xor(jw, 16));
  jw = max(jw, __shfl_xor(jw, 32));
  const uint4* X4 = (const uint4*)Xb;   // 8 uint4 per 64-elem row
  float acc[8] = {0.f, 0.f, 0.f, 0.f, 0.f, 0.f, 0.f, 0.f};
  #pragma unroll 4
  for (int j = 0; j < jw; ++j) {
    int v0 = __shfl(myidx, (g << 3) + j);   // all 64 lanes active
    if (j < jmax) {
      uint4 a = X4[(size_t)v0 * 8 + li];
      acc[0] += b2f(a.x & 0xffffu); acc[1] += b2f(a.x >> 16);
      acc[2] += b2f(a.y & 0xffffu); acc[3] += b2f(a.y >> 16);
      acc[4] += b2f(a.z & 0xffffu); acc[5] += b2f(a.z >> 16);
      acc[6] += b2f(a.w & 0xffffu); acc[7] += b2f(a.w >> 16);
    }
  }
  for (int j = 8; j < deg; ++j) {           // tail (deg>8)
    int v0 = perm[start + j];
    uint4 a = X4[(size_t)v0 * 8 + li];
    acc[0] += b2f(a.x & 0xffffu); acc[1] += b2f(a.x >> 16);
    acc[2] += b2f(a.y & 0xffffu); acc[3] += b2f(a.y >> 16);
    acc[4] += b2f(a.z & 0xffffu); acc[5] += b2f(a.z >> 16);
    acc[6] += b2f(a.w & 0xffffu); acc[7] += b2f(a.w >> 16);
  }
  if (valid) {
    float s = dege[e] / fmaxf((float)deg, 1.0f);
    uint4 r;
    r.x = (unsigned)f2b(acc[0] * s) | ((unsigned)f2b(acc[1] * s) << 16);
    r.y = (unsigned)f2b(acc[2] * s) | ((unsigned)f2b(acc[3] * s) << 16);
    r.z = (unsigned)f2b(acc[4] * s) | ((unsigned)f2b(acc[5] * s) << 16);
    r.w = (unsigned)f2b(acc[6] * s) | ((unsigned)f2b(acc[7] * s) << 16);
    ((uint4*)Xe)[(size_t)e * 8 + li] = r;
  }
}

// Fused node pass: block = 16 nodes = one MFMA strip. 4 waves × 4 nodes
// gather (16 lanes × uint2/row), degv scale, L2 norm, bf16 -> LDS strip;
// sync; each wave MFMAs 2 of 8 col-groups and stores f32 out.
#define SPAD 72
__global__ __launch_bounds__(256) void k_nodefused(
    const unsigned short* __restrict__ Xe, const int* __restrict__ off,
    const int* __restrict__ perm, const float* __restrict__ degv,
    const unsigned short* __restrict__ Wbf, const float* __restrict__ bias,
    float* __restrict__ out, int N, int M) {
  __shared__ __align__(16) unsigned short xnS[16][SPAD];
  int lane = threadIdx.x & 63;
  int wv = threadIdx.x >> 6;            // 0..3
  int g = lane >> 4, li = lane & 15;
  int nodeIn = wv * 4 + g;              // 0..15
  int node = blockIdx.x * 16 + nodeIn;
  bool valid = node < N;
  int start = 0, end = 0;
  if (valid) { start = off[M + node - 1]; end = off[M + node]; }  // node0: off[M-1]==E
  int deg = end - start;
  int myidx = (valid && li < deg) ? perm[start + li] : 0;
  int jmax = min(deg, 16);
  int jw = jmax;
  jw = max(jw, __shfl_xor(jw, 16));
  jw = max(jw, __shfl_xor(jw, 32));
  const uint2* Xe2 = (const uint2*)Xe;
  float4 acc = make_float4(0.f, 0.f, 0.f, 0.f);
  #pragma unroll 4
  for (int j = 0; j < jw; ++j) {
    int e0 = __shfl(myidx, (g << 4) + j);   // all 64 lanes active
    if (j < jmax) {
      uint2 a = Xe2[(size_t)e0 * 16 + li];
      acc.x += b2f(a.x & 0xffffu); acc.y += b2f(a.x >> 16);
      acc.z += b2f(a.y & 0xffffu); acc.w += b2f(a.y >> 16);
    }
  }
  for (int j = 16; j < deg; ++j) {
    int e0 = perm[start + j];
    uint2 a = Xe2[(size_t)e0 * 16 + li];
    acc.x += b2f(a.x & 0xffffu); acc.y += b2f(a.x >> 16);
    acc.z += b2f(a.y & 0xffffu); acc.w += b2f(a.y >> 16);
  }
  float dv = valid ? degv[node] : 0.f;
  acc.x *= dv; acc.y *= dv; acc.z *= dv; acc.w *= dv;
  float ss = acc.x * acc.x + acc.y * acc.y + acc.z * acc.z + acc.w * acc.w;
  #pragma unroll
  for (int o = 1; o <= 8; o <<= 1) ss += __shfl_xor(ss, o);  // within group
  float sc = ss > 0.0f ? 1.0f / sqrtf(ss) : 0.0f;
  ushort4 r4;
  r4.x = f2b(acc.x * sc); r4.y = f2b(acc.y * sc);
  r4.z = f2b(acc.z * sc); r4.w = f2b(acc.w * sc);
  *(ushort4*)&xnS[nodeIn][li * 4] = r4;
  __syncthreads();

  // MFMA phase: A frag row = lane&15, k = (lane>>4)*8 + j
  int r = lane & 15, h = lane >> 4;
  bf16x8 a0 = *(const bf16x8*)&xnS[r][h * 8];
  bf16x8 a1 = *(const bf16x8*)&xnS[r][32 + h * 8];
  int row0 = blockIdx.x * 16;
  #pragma unroll
  for (int cc = 0; cc < 2; ++cc) {
    int c = wv * 2 + cc;
    const unsigned short* wcol = Wbf + (size_t)(c * 16 + r) * DIN;
    bf16x8 b0 = *(const bf16x8*)&wcol[h * 8];
    bf16x8 b1 = *(const bf16x8*)&wcol[32 + h * 8];
    float bc = bias[c * 16 + r];
    f32x4 o4 = {bc, bc, bc, bc};
    o4 = __builtin_amdgcn_mfma_f32_16x16x32_bf16(a0, b0, o4, 0, 0, 0);
    o4 = __builtin_amdgcn_mfma_f32_16x16x32_bf16(a1, b1, o4, 0, 0, 0);
    #pragma unroll
    for (int q = 0; q < 4; ++q) {
      int row = row0 + h * 4 + q;
      if (row < N) out[(size_t)row * DOUT + c * 16 + r] = o4[q];
    }
  }
}

extern "C" void kernel_launch(void* const* d_in, const int* in_sizes, int n_in,
                              void* d_out, int out_size, void* d_ws, size_t ws_size,
                              hipStream_t stream) {
  const float* X      = (const float*)d_in[0];
  const int*   vertex = (const int*)d_in[1];
  const int*   edges  = (const int*)d_in[2];
  const float* dege   = (const float*)d_in[3];
  const float* degv   = (const float*)d_in[4];
  const float* W      = (const float*)d_in[5];
  const float* b      = (const float*)d_in[6];
  float* out = (float*)d_out;

  int N = in_sizes[0] / DIN;   // 100000
  int E = in_sizes[1];         // 1000000
  int M = in_sizes[3];         // 200000

  int NCH = (E + CH - 1) / CH;                 // 245
  int BKE = (M + FINE - 1) >> BSHIFT;          // 391
  int BKV = (N + FINE - 1) >> BSHIFT;          // 196
  int BK  = BKE + BKV;                         // 587

  // workspace layout
  unsigned short* Xe = (unsigned short*)d_ws;               // M*64 bf16 (25.6 MB)
  unsigned short* Xb = Xe + (size_t)M * DIN;                // N*64 bf16 (12.8 MB)
  int*   off  = (int*)(Xb + (size_t)N * DIN);               // M+N
  int*   perm = off + (M + N);                              // 2E (8 MB)
  unsigned* temp = (unsigned*)(perm + 2 * (size_t)E);       // 2E u32 (8 MB)
  int*   G    = (int*)(temp + 2 * (size_t)E);               // BK*NCH (575 KB)
  int*   rowTot = G + (size_t)BK * NCH;                     // BK
  int*   bucketBase = rowTot + BK;                          // BK+1
  int*   done = bucketBase + BK + 1;                        // 1
  size_t wOff = (((size_t)(done + 1 - (int*)d_ws) * 4) + 15) & ~(size_t)15;
  unsigned short* Wbf = (unsigned short*)((char*)d_ws + wOff);  // 8192 bf16

  int total4 = N * DIN / 4;
  k_p1<<<NCH + XB + 1, 256, 0, stream>>>(vertex, edges, G, X, Xb, W, Wbf, done,
                                         E, BKE, BK, NCH, total4);
  k_p1b<<<BK, 256, 0, stream>>>(G, rowTot, bucketBase, done, NCH, BK);
  p2_scatter<<<NCH, 256, 0, stream>>>(vertex, edges, G, bucketBase, temp,
                                      E, BKE, BK, NCH);
  p3_sort<<<BK, 256, 0, stream>>>(temp, bucketBase, off, perm, BKE, M, N);

  int edgeBlocks = (M + 31) / 32;        // 8 edges/wave, 4 waves/block
  k_edge<<<edgeBlocks, 256, 0, stream>>>(Xb, off, perm, dege, Xe, M);

  int nodeBlocks = (N + 15) / 16;        // one 16-row strip per block
  k_nodefused<<<nodeBlocks, 256, 0, stream>>>(Xe, off, perm, degv, Wbf, b,
                                              out, N, M);
}

// Round 13
// 135.680 us; speedup vs baseline: 2.0810x; 1.0218x over previous
//
#include <hip/hip_runtime.h>

// UniGCNConv2: bucketed counting sort (packed keys, no global atomics) ->
// X cast bf16 (fused into p1) -> gather segment-mean Xe (bf16 store, f32
// accum, 8 edges/wave) -> gather+degv+L2norm xn (bf16, 2 nodes per 16-lane
// group for 2x memory ILP) -> MFMA bf16 linear. 7 launches.
// N=100000, M=200000, E=1e6, D_IN=64, out 128.

#define DIN 64
#define DOUT 128
#define CH 4096
#define BSHIFT 9          // fine range 512
#define FINE 512
#define PAYBITS 18
#define PAYMASK ((1u << PAYBITS) - 1u)
#define XB 256            // xcast helper blocks fused into p1

typedef float f32x4 __attribute__((ext_vector_type(4)));
typedef short bf16x8 __attribute__((ext_vector_type(8)));

__device__ __forceinline__ unsigned short f2b(float f) {
  unsigned u = __float_as_uint(f);
  u = u + 0x7fffu + ((u >> 16) & 1u);   // RNE
  return (unsigned short)(u >> 16);
}
__device__ __forceinline__ float b2f(unsigned s) {
  return __uint_as_float(s << 16);
}

// ---- P1: blocks [0,NCH): coarse hist (int4 reads); [NCH,NCH+XB): X->bf16.
// Block 0 zeroes the done counter (replay-deterministic).
__global__ __launch_bounds__(256) void k_p1(
    const int* __restrict__ vertex, const int* __restrict__ edges,
    int* __restrict__ G, const float* __restrict__ X,
    unsigned short* __restrict__ Xb, int* __restrict__ done,
    int E, int BKE, int BK, int NCH, int total4) {
  if (blockIdx.x == 0 && threadIdx.x == 0) *done = 0;
  if (blockIdx.x >= (unsigned)NCH) {  // xcast role
    int xb = blockIdx.x - NCH;
    for (int i = xb * 256 + threadIdx.x; i < total4; i += XB * 256) {
      float4 a = ((const float4*)X)[i];
      ushort4 r;
      r.x = f2b(a.x); r.y = f2b(a.y); r.z = f2b(a.z); r.w = f2b(a.w);
      ((ushort4*)Xb)[i] = r;
    }
    return;
  }
  __shared__ int h[1024];
  for (int i = threadIdx.x; i < BK; i += 256) h[i] = 0;
  __syncthreads();
  int c = blockIdx.x;
  int s = c * CH, e_ = min(E, s + CH);
  int n4 = (e_ - s) >> 2;
  const int4* ep = (const int4*)(edges + s);
  const int4* vp = (const int4*)(vertex + s);
  for (int i = threadIdx.x; i < n4; i += 256) {
    int4 ee = ep[i], vv = vp[i];
    atomicAdd(&h[ee.x >> BSHIFT], 1); atomicAdd(&h[ee.y >> BSHIFT], 1);
    atomicAdd(&h[ee.z >> BSHIFT], 1); atomicAdd(&h[ee.w >> BSHIFT], 1);
    atomicAdd(&h[BKE + (vv.x >> BSHIFT)], 1); atomicAdd(&h[BKE + (vv.y >> BSHIFT)], 1);
    atomicAdd(&h[BKE + (vv.z >> BSHIFT)], 1); atomicAdd(&h[BKE + (vv.w >> BSHIFT)], 1);
  }
  for (int i = s + (n4 << 2) + threadIdx.x; i < e_; i += 256) {
    atomicAdd(&h[edges[i] >> BSHIFT], 1);
    atomicAdd(&h[BKE + (vertex[i] >> BSHIFT)], 1);
  }
  __syncthreads();
  for (int b = threadIdx.x; b < BK; b += 256) G[(size_t)b * NCH + c] = h[b];
}

// ---- P1b: per-bucket row scan across chunks; last block scans bucket totals.
__global__ __launch_bounds__(256) void k_p1b(
    int* __restrict__ G, int* __restrict__ rowTot, int* __restrict__ bucketBase,
    int* __restrict__ done, int NCH, int BK) {
  int b = blockIdx.x;
  int* row = G + (size_t)b * NCH;
  __shared__ int wsum[4];
  __shared__ int carry;
  __shared__ bool amLast;
  if (threadIdx.x == 0) carry = 0;
  __syncthreads();
  for (int base = 0; base < NCH; base += 256) {
    int i = base + threadIdx.x;
    int v = (i < NCH) ? row[i] : 0;
    int lane = threadIdx.x & 63, wid = threadIdx.x >> 6;
    int inc = v;
    #pragma unroll
    for (int o = 1; o < 64; o <<= 1) {
      int t = __shfl_up(inc, o);
      if (lane >= o) inc += t;
    }
    if (lane == 63) wsum[wid] = inc;
    __syncthreads();
    int woff = carry;
    for (int w = 0; w < wid; ++w) woff += wsum[w];
    int excl = woff + inc - v;
    if (i < NCH) row[i] = excl;
    __syncthreads();
    if (threadIdx.x == 0) carry += wsum[0] + wsum[1] + wsum[2] + wsum[3];
    __syncthreads();
  }
  if (threadIdx.x == 0) {
    rowTot[b] = carry;
    __threadfence();
    amLast = (atomicAdd(done, 1) == gridDim.x - 1);
  }
  __syncthreads();
  if (!amLast) return;

  if (threadIdx.x == 0) carry = 0;
  __syncthreads();
  for (int base = 0; base < BK; base += 256) {
    int i = base + threadIdx.x;
    int v = (i < BK) ? atomicAdd(&rowTot[i], 0) : 0;  // device-fresh read
    int lane = threadIdx.x & 63, wid = threadIdx.x >> 6;
    int inc = v;
    #pragma unroll
    for (int o = 1; o < 64; o <<= 1) {
      int t = __shfl_up(inc, o);
      if (lane >= o) inc += t;
    }
    if (lane == 63) wsum[wid] = inc;
    __syncthreads();
    int woff = carry;
    for (int w = 0; w < wid; ++w) woff += wsum[w];
    int excl = woff + inc - v;
    if (i < BK) bucketBase[i] = excl;
    __syncthreads();
    if (threadIdx.x == 0) carry += wsum[0] + wsum[1] + wsum[2] + wsum[3];
    __syncthreads();
  }
  if (threadIdx.x == 0) bucketBase[BK] = carry;
}

// ---- P2: scatter packed (fine,payload) via LDS cursors ----
__global__ __launch_bounds__(256) void p2_scatter(
    const int* __restrict__ vertex, const int* __restrict__ edges,
    const int* __restrict__ G, const int* __restrict__ bucketBase,
    unsigned* __restrict__ temp, int E, int BKE, int BK, int NCH) {
  __shared__ int curs[1024];
  int c = blockIdx.x;
  for (int b = threadIdx.x; b < BK; b += 256)
    curs[b] = bucketBase[b] + G[(size_t)b * NCH + c];
  __syncthreads();
  int s = c * CH, e_ = min(E, s + CH);
  for (int i = s + threadIdx.x; i < e_; i += 256) {
    int e = edges[i], v = vertex[i];
    int pE = atomicAdd(&curs[e >> BSHIFT], 1);
    temp[pE] = ((unsigned)(e & (FINE - 1)) << PAYBITS) | (unsigned)v;
    int pV = atomicAdd(&curs[BKE + (v >> BSHIFT)], 1);
    temp[pV] = ((unsigned)(v & (FINE - 1)) << PAYBITS) | (unsigned)e;
  }
}

// ---- P3: per-bucket fine counting sort -> off (inclusive ends) + perm ----
__global__ __launch_bounds__(256) void p3_sort(
    const unsigned* __restrict__ temp, const int* __restrict__ bucketBase,
    int* __restrict__ off, int* __restrict__ perm, int BKE, int M, int N) {
  __shared__ int hist[FINE];
  __shared__ int pos[FINE];
  __shared__ int wsum[4];
  int g = blockIdx.x;
  bool isE = g < BKE;
  int gg = isE ? g : g - BKE;
  int keyBase = gg << BSHIFT;
  int cap = isE ? M : N;
  int offBase = (isE ? 0 : M) + keyBase;
  int fineCount = min(FINE, cap - keyBase);
  int pairBase = bucketBase[g], pairEnd = bucketBase[g + 1];
  int cnt = pairEnd - pairBase;

  for (int i = threadIdx.x; i < FINE; i += 256) hist[i] = 0;
  __syncthreads();
  for (int i = threadIdx.x; i < cnt; i += 256)
    atomicAdd(&hist[temp[pairBase + i] >> PAYBITS], 1);
  __syncthreads();

  int t2 = threadIdx.x * 2;
  int a0 = hist[t2], a1 = hist[t2 + 1];
  int tsum = a0 + a1;
  int lane = threadIdx.x & 63, wid = threadIdx.x >> 6;
  int inc = tsum;
  #pragma unroll
  for (int o = 1; o < 64; o <<= 1) {
    int t = __shfl_up(inc, o);
    if (lane >= o) inc += t;
  }
  if (lane == 63) wsum[wid] = inc;
  __syncthreads();
  int woff = 0;
  for (int w = 0; w < wid; ++w) woff += wsum[w];
  int excl = woff + inc - tsum;
  pos[t2] = excl; pos[t2 + 1] = excl + a0;
  __syncthreads();

  for (int f = threadIdx.x; f < fineCount; f += 256)
    off[offBase + f] = pairBase + pos[f] + hist[f];
  for (int f = threadIdx.x; f < FINE; f += 256) pos[f] += pairBase;
  __syncthreads();

  for (int i = threadIdx.x; i < cnt; i += 256) {
    unsigned p = temp[pairBase + i];
    int q = atomicAdd(&pos[p >> PAYBITS], 1);
    perm[q] = (int)(p & PAYMASK);
  }
}

// ---- compute passes ----

// 8 hyperedges per wave, one per 8-lane group; 8 lanes × uint4 = 128B row.
__global__ __launch_bounds__(256) void k_edge(
    const unsigned short* __restrict__ Xb, const int* __restrict__ off,
    const int* __restrict__ perm, const float* __restrict__ dege,
    unsigned short* __restrict__ Xe, int M) {
  long long gid = (long long)blockIdx.x * 256 + threadIdx.x;
  int wv = (int)(gid >> 6);
  int lane = threadIdx.x & 63;
  int g = lane >> 3, li = lane & 7;     // 8 groups of 8 lanes
  int e = wv * 8 + g;
  bool valid = e < M;
  int start = 0, end = 0;
  if (valid) { start = e ? off[e - 1] : 0; end = off[e]; }
  int deg = end - start;
  int myidx = (valid && li < deg) ? perm[start + li] : 0;
  int jmax = min(deg, 8);
  int jw = jmax;
  jw = max(jw, __shfl_xor(jw, 8));
  jw = max(jw, __shfl_xor(jw, 16));
  jw = max(jw, __shfl_xor(jw, 32));
  const uint4* X4 = (const uint4*)Xb;   // 8 uint4 per 64-elem row
  float acc[8] = {0.f, 0.f, 0.f, 0.f, 0.f, 0.f, 0.f, 0.f};
  #pragma unroll 4
  for (int j = 0; j < jw; ++j) {
    int v0 = __shfl(myidx, (g << 3) + j);   // all 64 lanes active
    if (j < jmax) {
      uint4 a = X4[(size_t)v0 * 8 + li];
      acc[0] += b2f(a.x & 0xffffu); acc[1] += b2f(a.x >> 16);
      acc[2] += b2f(a.y & 0xffffu); acc[3] += b2f(a.y >> 16);
      acc[4] += b2f(a.z & 0xffffu); acc[5] += b2f(a.z >> 16);
      acc[6] += b2f(a.w & 0xffffu); acc[7] += b2f(a.w >> 16);
    }
  }
  for (int j = 8; j < deg; ++j) {           // tail (deg>8)
    int v0 = perm[start + j];
    uint4 a = X4[(size_t)v0 * 8 + li];
    acc[0] += b2f(a.x & 0xffffu); acc[1] += b2f(a.x >> 16);
    acc[2] += b2f(a.y & 0xffffu); acc[3] += b2f(a.y >> 16);
    acc[4] += b2f(a.z & 0xffffu); acc[5] += b2f(a.z >> 16);
    acc[6] += b2f(a.w & 0xffffu); acc[7] += b2f(a.w >> 16);
  }
  if (valid) {
    float s = dege[e] / fmaxf((float)deg, 1.0f);
    uint4 r;
    r.x = (unsigned)f2b(acc[0] * s) | ((unsigned)f2b(acc[1] * s) << 16);
    r.y = (unsigned)f2b(acc[2] * s) | ((unsigned)f2b(acc[3] * s) << 16);
    r.z = (unsigned)f2b(acc[4] * s) | ((unsigned)f2b(acc[5] * s) << 16);
    r.w = (unsigned)f2b(acc[6] * s) | ((unsigned)f2b(acc[7] * s) << 16);
    ((uint4*)Xe)[(size_t)e * 8 + li] = r;
  }
}

// Node aggregate: 8 nodes/wave — each 16-lane group owns TWO nodes (A,B)
// with independent accumulators/index streams for 2x memory ILP.
// Gather bf16 Xe rows (f32 accum), degv scale, L2 normalize, write bf16 xn.
__global__ __launch_bounds__(256) void k_nodeagg(
    const unsigned short* __restrict__ Xe, const int* __restrict__ off,
    const int* __restrict__ perm, const float* __restrict__ degv,
    unsigned short* __restrict__ xn, int N, int M) {
  long long gid = (long long)blockIdx.x * 256 + threadIdx.x;
  int wv = (int)(gid >> 6);
  int lane = threadIdx.x & 63;
  int g = lane >> 4, li = lane & 15;
  int base = wv * 8;
  int nA = base + g;
  int nB = base + 4 + g;
  bool vA = nA < N, vB = nB < N;
  int sA = 0, eA = 0, sB = 0, eB = 0;
  if (vA) { sA = off[M + nA - 1]; eA = off[M + nA]; }  // node0: off[M-1]==E
  if (vB) { sB = off[M + nB - 1]; eB = off[M + nB]; }
  int dA = eA - sA, dB = eB - sB;
  int myA = (vA && li < dA) ? perm[sA + li] : 0;
  int myB = (vB && li < dB) ? perm[sB + li] : 0;
  int jA = min(dA, 16), jB = min(dB, 16);
  int jw = max(jA, jB);
  jw = max(jw, __shfl_xor(jw, 16));
  jw = max(jw, __shfl_xor(jw, 32));
  const uint2* Xe2 = (const uint2*)Xe;
  float4 aA = make_float4(0.f, 0.f, 0.f, 0.f);
  float4 aB = make_float4(0.f, 0.f, 0.f, 0.f);
  #pragma unroll 2
  for (int j = 0; j < jw; ++j) {
    int iA = __shfl(myA, (g << 4) + j);   // all 64 lanes active
    int iB = __shfl(myB, (g << 4) + j);
    if (j < jA) {
      uint2 a = Xe2[(size_t)iA * 16 + li];
      aA.x += b2f(a.x & 0xffffu); aA.y += b2f(a.x >> 16);
      aA.z += b2f(a.y & 0xffffu); aA.w += b2f(a.y >> 16);
    }
    if (j < jB) {
      uint2 a = Xe2[(size_t)iB * 16 + li];
      aB.x += b2f(a.x & 0xffffu); aB.y += b2f(a.x >> 16);
      aB.z += b2f(a.y & 0xffffu); aB.w += b2f(a.y >> 16);
    }
  }
  for (int j = 16; j < dA; ++j) {          // rare tail
    int e0 = perm[sA + j];
    uint2 a = Xe2[(size_t)e0 * 16 + li];
    aA.x += b2f(a.x & 0xffffu); aA.y += b2f(a.x >> 16);
    aA.z += b2f(a.y & 0xffffu); aA.w += b2f(a.y >> 16);
  }
  for (int j = 16; j < dB; ++j) {
    int e0 = perm[sB + j];
    uint2 a = Xe2[(size_t)e0 * 16 + li];
    aB.x += b2f(a.x & 0xffffu); aB.y += b2f(a.x >> 16);
    aB.z += b2f(a.y & 0xffffu); aB.w += b2f(a.y >> 16);
  }
  float dvA = vA ? degv[nA] : 0.f;
  float dvB = vB ? degv[nB] : 0.f;
  aA.x *= dvA; aA.y *= dvA; aA.z *= dvA; aA.w *= dvA;
  aB.x *= dvB; aB.y *= dvB; aB.z *= dvB; aB.w *= dvB;
  float ssA = aA.x * aA.x + aA.y * aA.y + aA.z * aA.z + aA.w * aA.w;
  float ssB = aB.x * aB.x + aB.y * aB.y + aB.z * aB.z + aB.w * aB.w;
  #pragma unroll
  for (int o = 1; o <= 8; o <<= 1) {
    ssA += __shfl_xor(ssA, o);
    ssB += __shfl_xor(ssB, o);
  }
  float scA = ssA > 0.0f ? 1.0f / sqrtf(ssA) : 0.0f;
  float scB = ssB > 0.0f ? 1.0f / sqrtf(ssB) : 0.0f;
  if (vA) {
    ushort4 r;
    r.x = f2b(aA.x * scA); r.y = f2b(aA.y * scA);
    r.z = f2b(aA.z * scA); r.w = f2b(aA.w * scA);
    ((ushort4*)xn)[(size_t)nA * 16 + li] = r;
  }
  if (vB) {
    ushort4 r;
    r.x = f2b(aB.x * scB); r.y = f2b(aB.y * scB);
    r.z = f2b(aB.z * scB); r.w = f2b(aB.w * scB);
    ((ushort4*)xn)[(size_t)nB * 16 + li] = r;
  }
}

// out[N x 128] = xn(bf16) @ W + b via mfma_f32_16x16x32_bf16.
// A frag: row = lane&15, k = (lane>>4)*8 + j. B frag: col = lane&15, same k.
// C/D: col = lane&15, row = (lane>>4)*4 + reg  [m89-verified].
#define WPAD 72
__global__ __launch_bounds__(256) void k_linear(
    const unsigned short* __restrict__ xn, const float* __restrict__ W,
    const float* __restrict__ bias, float* __restrict__ out, int N) {
  __shared__ unsigned short Wt[DOUT * WPAD];
  for (int i = threadIdx.x; i < DIN * DOUT; i += 256) {
    int k = i >> 7, c = i & 127;   // W[k][c]
    Wt[c * WPAD + k] = f2b(W[i]);
  }
  __syncthreads();
  int lane = threadIdx.x & 63;
  int wid = threadIdx.x >> 6;
  int r = lane & 15, h = lane >> 4;

  bf16x8 Bf[8][2];
  #pragma unroll
  for (int c = 0; c < 8; ++c) {
    #pragma unroll
    for (int ks = 0; ks < 2; ++ks) {
      int col = c * 16 + r;
      int k0 = ks * 32 + h * 8;
      Bf[c][ks] = *(const bf16x8*)&Wt[col * WPAD + k0];
    }
  }
  float bcol[8];
  #pragma unroll
  for (int c = 0; c < 8; ++c) bcol[c] = bias[c * 16 + r];

  int strips = (N + 15) >> 4;
  for (int s = blockIdx.x * 4 + wid; s < strips; s += gridDim.x * 4) {
    int row0 = s << 4;
    const unsigned short* xrow = xn + (size_t)(row0 + r) * DIN;
    bf16x8 a0 = *(const bf16x8*)&xrow[h * 8];
    bf16x8 a1 = *(const bf16x8*)&xrow[32 + h * 8];
    #pragma unroll
    for (int c = 0; c < 8; ++c) {
      f32x4 acc = {bcol[c], bcol[c], bcol[c], bcol[c]};
      acc = __builtin_amdgcn_mfma_f32_16x16x32_bf16(a0, Bf[c][0], acc, 0, 0, 0);
      acc = __builtin_amdgcn_mfma_f32_16x16x32_bf16(a1, Bf[c][1], acc, 0, 0, 0);
      #pragma unroll
      for (int q = 0; q < 4; ++q)
        out[(size_t)(row0 + h * 4 + q) * DOUT + c * 16 + r] = acc[q];
    }
  }
}

extern "C" void kernel_launch(void* const* d_in, const int* in_sizes, int n_in,
                              void* d_out, int out_size, void* d_ws, size_t ws_size,
                              hipStream_t stream) {
  const float* X      = (const float*)d_in[0];
  const int*   vertex = (const int*)d_in[1];
  const int*   edges  = (const int*)d_in[2];
  const float* dege   = (const float*)d_in[3];
  const float* degv   = (const float*)d_in[4];
  const float* W      = (const float*)d_in[5];
  const float* b      = (const float*)d_in[6];
  float* out = (float*)d_out;

  int N = in_sizes[0] / DIN;   // 100000
  int E = in_sizes[1];         // 1000000
  int M = in_sizes[3];         // 200000

  int NCH = (E + CH - 1) / CH;                 // 245
  int BKE = (M + FINE - 1) >> BSHIFT;          // 391
  int BKV = (N + FINE - 1) >> BSHIFT;          // 196
  int BK  = BKE + BKV;                         // 587

  // workspace layout; temp (dead after p3) aliases xn (written after p3)
  unsigned short* Xe = (unsigned short*)d_ws;               // M*64 bf16 (25.6 MB)
  unsigned short* Xb = Xe + (size_t)M * DIN;                // N*64 bf16 (12.8 MB)
  int*   off  = (int*)(Xb + (size_t)N * DIN);               // M+N
  int*   perm = off + (M + N);                              // 2E (8 MB)
  char*  R    = (char*)(perm + 2 * (size_t)E);
  unsigned*       temp = (unsigned*)R;                      // 2E u32 (8 MB)
  unsigned short* xn   = (unsigned short*)R;                // N*64 bf16 (12.8 MB)
  size_t rBytes = (size_t)2 * E * 4;
  size_t xBytes = (size_t)N * DIN * 2;
  char*  R2   = R + (rBytes > xBytes ? rBytes : xBytes);
  int*   G    = (int*)R2;                                   // BK*NCH (575 KB)
  int*   rowTot = G + (size_t)BK * NCH;                     // BK
  int*   bucketBase = rowTot + BK;                          // BK+1
  int*   done = bucketBase + BK + 1;                        // 1

  int total4 = N * DIN / 4;
  k_p1<<<NCH + XB, 256, 0, stream>>>(vertex, edges, G, X, Xb, done,
                                     E, BKE, BK, NCH, total4);
  k_p1b<<<BK, 256, 0, stream>>>(G, rowTot, bucketBase, done, NCH, BK);
  p2_scatter<<<NCH, 256, 0, stream>>>(vertex, edges, G, bucketBase, temp,
                                      E, BKE, BK, NCH);
  p3_sort<<<BK, 256, 0, stream>>>(temp, bucketBase, off, perm, BKE, M, N);

  int edgeBlocks = (M + 31) / 32;        // 8 edges/wave, 4 waves/block
  k_edge<<<edgeBlocks, 256, 0, stream>>>(Xb, off, perm, dege, Xe, M);

  int nodeWaves = (N + 7) / 8;           // 8 nodes/wave
  int nodeBlocks = (nodeWaves + 3) / 4;
  k_nodeagg<<<nodeBlocks, 256, 0, stream>>>(Xe, off, perm, degv, xn, N, M);

  int strips = (N + 15) >> 4;
  int linBlocks = (strips + 3) / 4;      // one strip per wave
  k_linear<<<linBlocks, 256, 0, stream>>>(xn, W, b, out, N);
}

// Round 14
// 131.513 us; speedup vs baseline: 2.1470x; 1.0317x over previous
//
#include <hip/hip_runtime.h>

// UniGCNConv2: bucketed counting sort (packed keys, no global atomics) ->
// X cast bf16 (fused into p1) -> gather segment-mean Xe (bf16 store, f32
// accum, 8 edges/wave) -> gather+degv+L2norm xn (bf16, 8 nodes/wave, uint4
// loads, 2-register index prefetch) -> MFMA bf16 linear. 7 launches.
// N=100000, M=200000, E=1e6, D_IN=64, out 128.

#define DIN 64
#define DOUT 128
#define CH 4096
#define BSHIFT 9          // fine range 512
#define FINE 512
#define PAYBITS 18
#define PAYMASK ((1u << PAYBITS) - 1u)
#define XB 256            // xcast helper blocks fused into p1
#define STAGE 8192        // p3 LDS pair-staging capacity

typedef float f32x4 __attribute__((ext_vector_type(4)));
typedef short bf16x8 __attribute__((ext_vector_type(8)));

__device__ __forceinline__ unsigned short f2b(float f) {
  unsigned u = __float_as_uint(f);
  u = u + 0x7fffu + ((u >> 16) & 1u);   // RNE
  return (unsigned short)(u >> 16);
}
__device__ __forceinline__ float b2f(unsigned s) {
  return __uint_as_float(s << 16);
}

// ---- P1: blocks [0,NCH): coarse hist (int4 reads); [NCH,NCH+XB): X->bf16.
// Block 0 zeroes the done counter (replay-deterministic).
__global__ __launch_bounds__(256) void k_p1(
    const int* __restrict__ vertex, const int* __restrict__ edges,
    int* __restrict__ G, const float* __restrict__ X,
    unsigned short* __restrict__ Xb, int* __restrict__ done,
    int E, int BKE, int BK, int NCH, int total4) {
  if (blockIdx.x == 0 && threadIdx.x == 0) *done = 0;
  if (blockIdx.x >= (unsigned)NCH) {  // xcast role
    int xb = blockIdx.x - NCH;
    for (int i = xb * 256 + threadIdx.x; i < total4; i += XB * 256) {
      float4 a = ((const float4*)X)[i];
      ushort4 r;
      r.x = f2b(a.x); r.y = f2b(a.y); r.z = f2b(a.z); r.w = f2b(a.w);
      ((ushort4*)Xb)[i] = r;
    }
    return;
  }
  __shared__ int h[1024];
  for (int i = threadIdx.x; i < BK; i += 256) h[i] = 0;
  __syncthreads();
  int c = blockIdx.x;
  int s = c * CH, e_ = min(E, s + CH);
  int n4 = (e_ - s) >> 2;
  const int4* ep = (const int4*)(edges + s);
  const int4* vp = (const int4*)(vertex + s);
  for (int i = threadIdx.x; i < n4; i += 256) {
    int4 ee = ep[i], vv = vp[i];
    atomicAdd(&h[ee.x >> BSHIFT], 1); atomicAdd(&h[ee.y >> BSHIFT], 1);
    atomicAdd(&h[ee.z >> BSHIFT], 1); atomicAdd(&h[ee.w >> BSHIFT], 1);
    atomicAdd(&h[BKE + (vv.x >> BSHIFT)], 1); atomicAdd(&h[BKE + (vv.y >> BSHIFT)], 1);
    atomicAdd(&h[BKE + (vv.z >> BSHIFT)], 1); atomicAdd(&h[BKE + (vv.w >> BSHIFT)], 1);
  }
  for (int i = s + (n4 << 2) + threadIdx.x; i < e_; i += 256) {
    atomicAdd(&h[edges[i] >> BSHIFT], 1);
    atomicAdd(&h[BKE + (vertex[i] >> BSHIFT)], 1);
  }
  __syncthreads();
  for (int b = threadIdx.x; b < BK; b += 256) G[(size_t)b * NCH + c] = h[b];
}

// ---- P1b: per-bucket row scan across chunks; last block scans bucket totals.
__global__ __launch_bounds__(256) void k_p1b(
    int* __restrict__ G, int* __restrict__ rowTot, int* __restrict__ bucketBase,
    int* __restrict__ done, int NCH, int BK) {
  int b = blockIdx.x;
  int* row = G + (size_t)b * NCH;
  __shared__ int wsum[4];
  __shared__ int carry;
  __shared__ bool amLast;
  if (threadIdx.x == 0) carry = 0;
  __syncthreads();
  for (int base = 0; base < NCH; base += 256) {
    int i = base + threadIdx.x;
    int v = (i < NCH) ? row[i] : 0;
    int lane = threadIdx.x & 63, wid = threadIdx.x >> 6;
    int inc = v;
    #pragma unroll
    for (int o = 1; o < 64; o <<= 1) {
      int t = __shfl_up(inc, o);
      if (lane >= o) inc += t;
    }
    if (lane == 63) wsum[wid] = inc;
    __syncthreads();
    int woff = carry;
    for (int w = 0; w < wid; ++w) woff += wsum[w];
    int excl = woff + inc - v;
    if (i < NCH) row[i] = excl;
    __syncthreads();
    if (threadIdx.x == 0) carry += wsum[0] + wsum[1] + wsum[2] + wsum[3];
    __syncthreads();
  }
  if (threadIdx.x == 0) {
    rowTot[b] = carry;
    __threadfence();
    amLast = (atomicAdd(done, 1) == gridDim.x - 1);
  }
  __syncthreads();
  if (!amLast) return;

  if (threadIdx.x == 0) carry = 0;
  __syncthreads();
  for (int base = 0; base < BK; base += 256) {
    int i = base + threadIdx.x;
    int v = (i < BK) ? atomicAdd(&rowTot[i], 0) : 0;  // device-fresh read
    int lane = threadIdx.x & 63, wid = threadIdx.x >> 6;
    int inc = v;
    #pragma unroll
    for (int o = 1; o < 64; o <<= 1) {
      int t = __shfl_up(inc, o);
      if (lane >= o) inc += t;
    }
    if (lane == 63) wsum[wid] = inc;
    __syncthreads();
    int woff = carry;
    for (int w = 0; w < wid; ++w) woff += wsum[w];
    int excl = woff + inc - v;
    if (i < BK) bucketBase[i] = excl;
    __syncthreads();
    if (threadIdx.x == 0) carry += wsum[0] + wsum[1] + wsum[2] + wsum[3];
    __syncthreads();
  }
  if (threadIdx.x == 0) bucketBase[BK] = carry;
}

// ---- P2: scatter packed (fine,payload) via LDS cursors; int4 pair reads ----
__global__ __launch_bounds__(256) void p2_scatter(
    const int* __restrict__ vertex, const int* __restrict__ edges,
    const int* __restrict__ G, const int* __restrict__ bucketBase,
    unsigned* __restrict__ temp, int E, int BKE, int BK, int NCH) {
  __shared__ int curs[1024];
  int c = blockIdx.x;
  for (int b = threadIdx.x; b < BK; b += 256)
    curs[b] = bucketBase[b] + G[(size_t)b * NCH + c];
  __syncthreads();
  int s = c * CH, e_ = min(E, s + CH);
  int n4 = (e_ - s) >> 2;
  const int4* ep = (const int4*)(edges + s);
  const int4* vp = (const int4*)(vertex + s);
  for (int i = threadIdx.x; i < n4; i += 256) {
    int4 ee = ep[i], vv = vp[i];
    int p;
    p = atomicAdd(&curs[ee.x >> BSHIFT], 1);
    temp[p] = ((unsigned)(ee.x & (FINE - 1)) << PAYBITS) | (unsigned)vv.x;
    p = atomicAdd(&curs[BKE + (vv.x >> BSHIFT)], 1);
    temp[p] = ((unsigned)(vv.x & (FINE - 1)) << PAYBITS) | (unsigned)ee.x;
    p = atomicAdd(&curs[ee.y >> BSHIFT], 1);
    temp[p] = ((unsigned)(ee.y & (FINE - 1)) << PAYBITS) | (unsigned)vv.y;
    p = atomicAdd(&curs[BKE + (vv.y >> BSHIFT)], 1);
    temp[p] = ((unsigned)(vv.y & (FINE - 1)) << PAYBITS) | (unsigned)ee.y;
    p = atomicAdd(&curs[ee.z >> BSHIFT], 1);
    temp[p] = ((unsigned)(ee.z & (FINE - 1)) << PAYBITS) | (unsigned)vv.z;
    p = atomicAdd(&curs[BKE + (vv.z >> BSHIFT)], 1);
    temp[p] = ((unsigned)(vv.z & (FINE - 1)) << PAYBITS) | (unsigned)ee.z;
    p = atomicAdd(&curs[ee.w >> BSHIFT], 1);
    temp[p] = ((unsigned)(ee.w & (FINE - 1)) << PAYBITS) | (unsigned)vv.w;
    p = atomicAdd(&curs[BKE + (vv.w >> BSHIFT)], 1);
    temp[p] = ((unsigned)(vv.w & (FINE - 1)) << PAYBITS) | (unsigned)ee.w;
  }
  for (int i = s + (n4 << 2) + threadIdx.x; i < e_; i += 256) {
    int e = edges[i], v = vertex[i];
    int pE = atomicAdd(&curs[e >> BSHIFT], 1);
    temp[pE] = ((unsigned)(e & (FINE - 1)) << PAYBITS) | (unsigned)v;
    int pV = atomicAdd(&curs[BKE + (v >> BSHIFT)], 1);
    temp[pV] = ((unsigned)(v & (FINE - 1)) << PAYBITS) | (unsigned)e;
  }
}

// ---- P3: per-bucket fine counting sort -> off (inclusive ends) + perm.
// Pairs staged in LDS (cnt <= STAGE always for this distribution; fallback kept).
__global__ __launch_bounds__(256) void p3_sort(
    const unsigned* __restrict__ temp, const int* __restrict__ bucketBase,
    int* __restrict__ off, int* __restrict__ perm, int BKE, int M, int N) {
  __shared__ int hist[FINE];
  __shared__ int pos[FINE];
  __shared__ int wsum[4];
  __shared__ unsigned pairsS[STAGE];
  int g = blockIdx.x;
  bool isE = g < BKE;
  int gg = isE ? g : g - BKE;
  int keyBase = gg << BSHIFT;
  int cap = isE ? M : N;
  int offBase = (isE ? 0 : M) + keyBase;
  int fineCount = min(FINE, cap - keyBase);
  int pairBase = bucketBase[g], pairEnd = bucketBase[g + 1];
  int cnt = pairEnd - pairBase;
  bool staged = cnt <= STAGE;

  for (int i = threadIdx.x; i < FINE; i += 256) hist[i] = 0;
  __syncthreads();
  if (staged) {
    for (int i = threadIdx.x; i < cnt; i += 256) {
      unsigned p = temp[pairBase + i];
      pairsS[i] = p;
      atomicAdd(&hist[p >> PAYBITS], 1);
    }
  } else {
    for (int i = threadIdx.x; i < cnt; i += 256)
      atomicAdd(&hist[temp[pairBase + i] >> PAYBITS], 1);
  }
  __syncthreads();

  int t2 = threadIdx.x * 2;
  int a0 = hist[t2], a1 = hist[t2 + 1];
  int tsum = a0 + a1;
  int lane = threadIdx.x & 63, wid = threadIdx.x >> 6;
  int inc = tsum;
  #pragma unroll
  for (int o = 1; o < 64; o <<= 1) {
    int t = __shfl_up(inc, o);
    if (lane >= o) inc += t;
  }
  if (lane == 63) wsum[wid] = inc;
  __syncthreads();
  int woff = 0;
  for (int w = 0; w < wid; ++w) woff += wsum[w];
  int excl = woff + inc - tsum;
  pos[t2] = excl; pos[t2 + 1] = excl + a0;
  __syncthreads();

  for (int f = threadIdx.x; f < fineCount; f += 256)
    off[offBase + f] = pairBase + pos[f] + hist[f];
  for (int f = threadIdx.x; f < FINE; f += 256) pos[f] += pairBase;
  __syncthreads();

  if (staged) {
    for (int i = threadIdx.x; i < cnt; i += 256) {
      unsigned p = pairsS[i];
      int q = atomicAdd(&pos[p >> PAYBITS], 1);
      perm[q] = (int)(p & PAYMASK);
    }
  } else {
    for (int i = threadIdx.x; i < cnt; i += 256) {
      unsigned p = temp[pairBase + i];
      int q = atomicAdd(&pos[p >> PAYBITS], 1);
      perm[q] = (int)(p & PAYMASK);
    }
  }
}

// ---- compute passes ----

// 8 hyperedges per wave, one per 8-lane group; 8 lanes × uint4 = 128B row.
__global__ __launch_bounds__(256) void k_edge(
    const unsigned short* __restrict__ Xb, const int* __restrict__ off,
    const int* __restrict__ perm, const float* __restrict__ dege,
    unsigned short* __restrict__ Xe, int M) {
  long long gid = (long long)blockIdx.x * 256 + threadIdx.x;
  int wv = (int)(gid >> 6);
  int lane = threadIdx.x & 63;
  int g = lane >> 3, li = lane & 7;     // 8 groups of 8 lanes
  int e = wv * 8 + g;
  bool valid = e < M;
  int start = 0, end = 0;
  if (valid) { start = e ? off[e - 1] : 0; end = off[e]; }
  int deg = end - start;
  int myidx = (valid && li < deg) ? perm[start + li] : 0;
  int jmax = min(deg, 8);
  int jw = jmax;
  jw = max(jw, __shfl_xor(jw, 8));
  jw = max(jw, __shfl_xor(jw, 16));
  jw = max(jw, __shfl_xor(jw, 32));
  const uint4* X4 = (const uint4*)Xb;   // 8 uint4 per 64-elem row
  float acc[8] = {0.f, 0.f, 0.f, 0.f, 0.f, 0.f, 0.f, 0.f};
  #pragma unroll 4
  for (int j = 0; j < jw; ++j) {
    int v0 = __shfl(myidx, (g << 3) + j);   // all 64 lanes active
    if (j < jmax) {
      uint4 a = X4[(size_t)v0 * 8 + li];
      acc[0] += b2f(a.x & 0xffffu); acc[1] += b2f(a.x >> 16);
      acc[2] += b2f(a.y & 0xffffu); acc[3] += b2f(a.y >> 16);
      acc[4] += b2f(a.z & 0xffffu); acc[5] += b2f(a.z >> 16);
      acc[6] += b2f(a.w & 0xffffu); acc[7] += b2f(a.w >> 16);
    }
  }
  for (int j = 8; j < deg; ++j) {           // tail (deg>8)
    int v0 = perm[start + j];
    uint4 a = X4[(size_t)v0 * 8 + li];
    acc[0] += b2f(a.x & 0xffffu); acc[1] += b2f(a.x >> 16);
    acc[2] += b2f(a.y & 0xffffu); acc[3] += b2f(a.y >> 16);
    acc[4] += b2f(a.z & 0xffffu); acc[5] += b2f(a.z >> 16);
    acc[6] += b2f(a.w & 0xffffu); acc[7] += b2f(a.w >> 16);
  }
  if (valid) {
    float s = dege[e] / fmaxf((float)deg, 1.0f);
    uint4 r;
    r.x = (unsigned)f2b(acc[0] * s) | ((unsigned)f2b(acc[1] * s) << 16);
    r.y = (unsigned)f2b(acc[2] * s) | ((unsigned)f2b(acc[3] * s) << 16);
    r.z = (unsigned)f2b(acc[4] * s) | ((unsigned)f2b(acc[5] * s) << 16);
    r.w = (unsigned)f2b(acc[6] * s) | ((unsigned)f2b(acc[7] * s) << 16);
    ((uint4*)Xe)[(size_t)e * 8 + li] = r;
  }
}

// Node aggregate: 8 nodes/wave, one per 8-lane group; 8 lanes × uint4 row
// loads; 2-register index prefetch (my0 for j<8, my1 for j in [8,16)).
// Gather bf16 Xe rows (f32 accum), degv scale, L2 normalize, write bf16 xn.
__global__ __launch_bounds__(256) void k_nodeagg(
    const unsigned short* __restrict__ Xe, const int* __restrict__ off,
    const int* __restrict__ perm, const float* __restrict__ degv,
    unsigned short* __restrict__ xn, int N, int M) {
  long long gid = (long long)blockIdx.x * 256 + threadIdx.x;
  int wv = (int)(gid >> 6);
  int lane = threadIdx.x & 63;
  int g = lane >> 3, li = lane & 7;     // 8 groups of 8 lanes
  int node = wv * 8 + g;
  bool valid = node < N;
  int start = 0, end = 0;
  if (valid) { start = off[M + node - 1]; end = off[M + node]; }  // node0: off[M-1]==E
  int deg = end - start;
  int my0 = (valid && li < deg) ? perm[start + li] : 0;
  int my1 = (valid && 8 + li < deg) ? perm[start + 8 + li] : 0;
  int jmax0 = min(deg, 8);
  int jmax1 = min(max(deg - 8, 0), 8);
  int jw0 = jmax0, jw1 = jmax1;
  jw0 = max(jw0, __shfl_xor(jw0, 8)); jw1 = max(jw1, __shfl_xor(jw1, 8));
  jw0 = max(jw0, __shfl_xor(jw0, 16)); jw1 = max(jw1, __shfl_xor(jw1, 16));
  jw0 = max(jw0, __shfl_xor(jw0, 32)); jw1 = max(jw1, __shfl_xor(jw1, 32));
  const uint4* Xe4 = (const uint4*)Xe;  // 8 uint4 per 64-elem row
  float acc[8] = {0.f, 0.f, 0.f, 0.f, 0.f, 0.f, 0.f, 0.f};
  #pragma unroll 4
  for (int j = 0; j < jw0; ++j) {
    int e0 = __shfl(my0, (g << 3) + j);   // all 64 lanes active
    if (j < jmax0) {
      uint4 a = Xe4[(size_t)e0 * 8 + li];
      acc[0] += b2f(a.x & 0xffffu); acc[1] += b2f(a.x >> 16);
      acc[2] += b2f(a.y & 0xffffu); acc[3] += b2f(a.y >> 16);
      acc[4] += b2f(a.z & 0xffffu); acc[5] += b2f(a.z >> 16);
      acc[6] += b2f(a.w & 0xffffu); acc[7] += b2f(a.w >> 16);
    }
  }
  #pragma unroll 4
  for (int j = 0; j < jw1; ++j) {
    int e0 = __shfl(my1, (g << 3) + j);   // all 64 lanes active
    if (j < jmax1) {
      uint4 a = Xe4[(size_t)e0 * 8 + li];
      acc[0] += b2f(a.x & 0xffffu); acc[1] += b2f(a.x >> 16);
      acc[2] += b2f(a.y & 0xffffu); acc[3] += b2f(a.y >> 16);
      acc[4] += b2f(a.z & 0xffffu); acc[5] += b2f(a.z >> 16);
      acc[6] += b2f(a.w & 0xffffu); acc[7] += b2f(a.w >> 16);
    }
  }
  for (int j = 16; j < deg; ++j) {        // tail (deg>16), ~2% of nodes
    int e0 = perm[start + j];
    uint4 a = Xe4[(size_t)e0 * 8 + li];
    acc[0] += b2f(a.x & 0xffffu); acc[1] += b2f(a.x >> 16);
    acc[2] += b2f(a.y & 0xffffu); acc[3] += b2f(a.y >> 16);
    acc[4] += b2f(a.z & 0xffffu); acc[5] += b2f(a.z >> 16);
    acc[6] += b2f(a.w & 0xffffu); acc[7] += b2f(a.w >> 16);
  }
  float dv = valid ? degv[node] : 0.f;
  float ss = 0.f;
  #pragma unroll
  for (int i = 0; i < 8; ++i) { acc[i] *= dv; ss += acc[i] * acc[i]; }
  #pragma unroll
  for (int o = 1; o <= 4; o <<= 1) ss += __shfl_xor(ss, o);  // within group
  float sc = ss > 0.0f ? 1.0f / sqrtf(ss) : 0.0f;
  if (valid) {
    uint4 r;
    r.x = (unsigned)f2b(acc[0] * sc) | ((unsigned)f2b(acc[1] * sc) << 16);
    r.y = (unsigned)f2b(acc[2] * sc) | ((unsigned)f2b(acc[3] * sc) << 16);
    r.z = (unsigned)f2b(acc[4] * sc) | ((unsigned)f2b(acc[5] * sc) << 16);
    r.w = (unsigned)f2b(acc[6] * sc) | ((unsigned)f2b(acc[7] * sc) << 16);
    ((uint4*)xn)[(size_t)node * 8 + li] = r;
  }
}

// out[N x 128] = xn(bf16) @ W + b via mfma_f32_16x16x32_bf16.
// A frag: row = lane&15, k = (lane>>4)*8 + j. B frag: col = lane&15, same k.
// C/D: col = lane&15, row = (lane>>4)*4 + reg  [m89-verified].
#define WPAD 72
__global__ __launch_bounds__(256) void k_linear(
    const unsigned short* __restrict__ xn, const float* __restrict__ W,
    const float* __restrict__ bias, float* __restrict__ out, int N) {
  __shared__ unsigned short Wt[DOUT * WPAD];
  for (int i = threadIdx.x; i < DIN * DOUT; i += 256) {
    int k = i >> 7, c = i & 127;   // W[k][c]
    Wt[c * WPAD + k] = f2b(W[i]);
  }
  __syncthreads();
  int lane = threadIdx.x & 63;
  int wid = threadIdx.x >> 6;
  int r = lane & 15, h = lane >> 4;

  bf16x8 Bf[8][2];
  #pragma unroll
  for (int c = 0; c < 8; ++c) {
    #pragma unroll
    for (int ks = 0; ks < 2; ++ks) {
      int col = c * 16 + r;
      int k0 = ks * 32 + h * 8;
      Bf[c][ks] = *(const bf16x8*)&Wt[col * WPAD + k0];
    }
  }
  float bcol[8];
  #pragma unroll
  for (int c = 0; c < 8; ++c) bcol[c] = bias[c * 16 + r];

  int strips = (N + 15) >> 4;
  for (int s = blockIdx.x * 4 + wid; s < strips; s += gridDim.x * 4) {
    int row0 = s << 4;
    const unsigned short* xrow = xn + (size_t)(row0 + r) * DIN;
    bf16x8 a0 = *(const bf16x8*)&xrow[h * 8];
    bf16x8 a1 = *(const bf16x8*)&xrow[32 + h * 8];
    #pragma unroll
    for (int c = 0; c < 8; ++c) {
      f32x4 acc = {bcol[c], bcol[c], bcol[c], bcol[c]};
      acc = __builtin_amdgcn_mfma_f32_16x16x32_bf16(a0, Bf[c][0], acc, 0, 0, 0);
      acc = __builtin_amdgcn_mfma_f32_16x16x32_bf16(a1, Bf[c][1], acc, 0, 0, 0);
      #pragma unroll
      for (int q = 0; q < 4; ++q)
        out[(size_t)(row0 + h * 4 + q) * DOUT + c * 16 + r] = acc[q];
    }
  }
}

extern "C" void kernel_launch(void* const* d_in, const int* in_sizes, int n_in,
                              void* d_out, int out_size, void* d_ws, size_t ws_size,
                              hipStream_t stream) {
  const float* X      = (const float*)d_in[0];
  const int*   vertex = (const int*)d_in[1];
  const int*   edges  = (const int*)d_in[2];
  const float* dege   = (const float*)d_in[3];
  const float* degv   = (const float*)d_in[4];
  const float* W      = (const float*)d_in[5];
  const float* b      = (const float*)d_in[6];
  float* out = (float*)d_out;

  int N = in_sizes[0] / DIN;   // 100000
  int E = in_sizes[1];         // 1000000
  int M = in_sizes[3];         // 200000

  int NCH = (E + CH - 1) / CH;                 // 245
  int BKE = (M + FINE - 1) >> BSHIFT;          // 391
  int BKV = (N + FINE - 1) >> BSHIFT;          // 196
  int BK  = BKE + BKV;                         // 587

  // workspace layout; temp (dead after p3) aliases xn (written after p3)
  unsigned short* Xe = (unsigned short*)d_ws;               // M*64 bf16 (25.6 MB)
  unsigned short* Xb = Xe + (size_t)M * DIN;                // N*64 bf16 (12.8 MB)
  int*   off  = (int*)(Xb + (size_t)N * DIN);               // M+N
  int*   perm = off + (M + N);                              // 2E (8 MB)
  char*  R    = (char*)(perm + 2 * (size_t)E);
  unsigned*       temp = (unsigned*)R;                      // 2E u32 (8 MB)
  unsigned short* xn   = (unsigned short*)R;                // N*64 bf16 (12.8 MB)
  size_t rBytes = (size_t)2 * E * 4;
  size_t xBytes = (size_t)N * DIN * 2;
  char*  R2   = R + (rBytes > xBytes ? rBytes : xBytes);
  int*   G    = (int*)R2;                                   // BK*NCH (575 KB)
  int*   rowTot = G + (size_t)BK * NCH;                     // BK
  int*   bucketBase = rowTot + BK;                          // BK+1
  int*   done = bucketBase + BK + 1;                        // 1

  int total4 = N * DIN / 4;
  k_p1<<<NCH + XB, 256, 0, stream>>>(vertex, edges, G, X, Xb, done,
                                     E, BKE, BK, NCH, total4);
  k_p1b<<<BK, 256, 0, stream>>>(G, rowTot, bucketBase, done, NCH, BK);
  p2_scatter<<<NCH, 256, 0, stream>>>(vertex, edges, G, bucketBase, temp,
                                      E, BKE, BK, NCH);
  p3_sort<<<BK, 256, 0, stream>>>(temp, bucketBase, off, perm, BKE, M, N);

  int edgeBlocks = (M + 31) / 32;        // 8 edges/wave, 4 waves/block
  k_edge<<<edgeBlocks, 256, 0, stream>>>(Xb, off, perm, dege, Xe, M);

  int nodeWaves = (N + 7) / 8;           // 8 nodes/wave
  int nodeBlocks = (nodeWaves + 3) / 4;
  k_nodeagg<<<nodeBlocks, 256, 0, stream>>>(Xe, off, perm, degv, xn, N, M);

  int strips = (N + 15) >> 4;
  int linBlocks = (strips + 3) / 4;      // one strip per wave
  k_linear<<<linBlocks, 256, 0, stream>>>(xn, W, b, out, N);
}

// Round 15
// 130.439 us; speedup vs baseline: 2.1646x; 1.0082x over previous
//
#include <hip/hip_runtime.h>

// UniGCNConv2: bucketed counting sort (packed keys, no global atomics) ->
// X cast bf16 (fused into p1) -> gather segment-mean Xe (bf16 store, f32
// accum, 8 edges/wave) -> gather+degv+L2norm xn (bf16, 8 nodes/wave, uint4
// loads, 2-register index prefetch) -> MFMA bf16 linear. 7 launches.
// r14: p1/p2 at 512 threads (2x wave parallelism, same write-combining).
// N=100000, M=200000, E=1e6, D_IN=64, out 128.

#define DIN 64
#define DOUT 128
#define CH 4096
#define BSHIFT 9          // fine range 512
#define FINE 512
#define PAYBITS 18
#define PAYMASK ((1u << PAYBITS) - 1u)
#define XB 256            // xcast helper blocks fused into p1
#define STAGE 8192        // p3 LDS pair-staging capacity

typedef float f32x4 __attribute__((ext_vector_type(4)));
typedef short bf16x8 __attribute__((ext_vector_type(8)));

__device__ __forceinline__ unsigned short f2b(float f) {
  unsigned u = __float_as_uint(f);
  u = u + 0x7fffu + ((u >> 16) & 1u);   // RNE
  return (unsigned short)(u >> 16);
}
__device__ __forceinline__ float b2f(unsigned s) {
  return __uint_as_float(s << 16);
}

// ---- P1 (512 thr): blocks [0,NCH): coarse hist (int4 reads);
// [NCH,NCH+XB): X->bf16. Block 0 zeroes the done counter.
__global__ __launch_bounds__(512) void k_p1(
    const int* __restrict__ vertex, const int* __restrict__ edges,
    int* __restrict__ G, const float* __restrict__ X,
    unsigned short* __restrict__ Xb, int* __restrict__ done,
    int E, int BKE, int BK, int NCH, int total4) {
  if (blockIdx.x == 0 && threadIdx.x == 0) *done = 0;
  if (blockIdx.x >= (unsigned)NCH) {  // xcast role
    int xb = blockIdx.x - NCH;
    for (int i = xb * 512 + threadIdx.x; i < total4; i += XB * 512) {
      float4 a = ((const float4*)X)[i];
      ushort4 r;
      r.x = f2b(a.x); r.y = f2b(a.y); r.z = f2b(a.z); r.w = f2b(a.w);
      ((ushort4*)Xb)[i] = r;
    }
    return;
  }
  __shared__ int h[1024];
  for (int i = threadIdx.x; i < BK; i += 512) h[i] = 0;
  __syncthreads();
  int c = blockIdx.x;
  int s = c * CH, e_ = min(E, s + CH);
  int n4 = (e_ - s) >> 2;
  const int4* ep = (const int4*)(edges + s);
  const int4* vp = (const int4*)(vertex + s);
  for (int i = threadIdx.x; i < n4; i += 512) {
    int4 ee = ep[i], vv = vp[i];
    atomicAdd(&h[ee.x >> BSHIFT], 1); atomicAdd(&h[ee.y >> BSHIFT], 1);
    atomicAdd(&h[ee.z >> BSHIFT], 1); atomicAdd(&h[ee.w >> BSHIFT], 1);
    atomicAdd(&h[BKE + (vv.x >> BSHIFT)], 1); atomicAdd(&h[BKE + (vv.y >> BSHIFT)], 1);
    atomicAdd(&h[BKE + (vv.z >> BSHIFT)], 1); atomicAdd(&h[BKE + (vv.w >> BSHIFT)], 1);
  }
  for (int i = s + (n4 << 2) + threadIdx.x; i < e_; i += 512) {
    atomicAdd(&h[edges[i] >> BSHIFT], 1);
    atomicAdd(&h[BKE + (vertex[i] >> BSHIFT)], 1);
  }
  __syncthreads();
  for (int b = threadIdx.x; b < BK; b += 512) G[(size_t)b * NCH + c] = h[b];
}

// ---- P1b: per-bucket row scan across chunks; last block scans bucket totals.
__global__ __launch_bounds__(256) void k_p1b(
    int* __restrict__ G, int* __restrict__ rowTot, int* __restrict__ bucketBase,
    int* __restrict__ done, int NCH, int BK) {
  int b = blockIdx.x;
  int* row = G + (size_t)b * NCH;
  __shared__ int wsum[4];
  __shared__ int carry;
  __shared__ bool amLast;
  if (threadIdx.x == 0) carry = 0;
  __syncthreads();
  for (int base = 0; base < NCH; base += 256) {
    int i = base + threadIdx.x;
    int v = (i < NCH) ? row[i] : 0;
    int lane = threadIdx.x & 63, wid = threadIdx.x >> 6;
    int inc = v;
    #pragma unroll
    for (int o = 1; o < 64; o <<= 1) {
      int t = __shfl_up(inc, o);
      if (lane >= o) inc += t;
    }
    if (lane == 63) wsum[wid] = inc;
    __syncthreads();
    int woff = carry;
    for (int w = 0; w < wid; ++w) woff += wsum[w];
    int excl = woff + inc - v;
    if (i < NCH) row[i] = excl;
    __syncthreads();
    if (threadIdx.x == 0) carry += wsum[0] + wsum[1] + wsum[2] + wsum[3];
    __syncthreads();
  }
  if (threadIdx.x == 0) {
    rowTot[b] = carry;
    __threadfence();
    amLast = (atomicAdd(done, 1) == gridDim.x - 1);
  }
  __syncthreads();
  if (!amLast) return;

  if (threadIdx.x == 0) carry = 0;
  __syncthreads();
  for (int base = 0; base < BK; base += 256) {
    int i = base + threadIdx.x;
    int v = (i < BK) ? atomicAdd(&rowTot[i], 0) : 0;  // device-fresh read
    int lane = threadIdx.x & 63, wid = threadIdx.x >> 6;
    int inc = v;
    #pragma unroll
    for (int o = 1; o < 64; o <<= 1) {
      int t = __shfl_up(inc, o);
      if (lane >= o) inc += t;
    }
    if (lane == 63) wsum[wid] = inc;
    __syncthreads();
    int woff = carry;
    for (int w = 0; w < wid; ++w) woff += wsum[w];
    int excl = woff + inc - v;
    if (i < BK) bucketBase[i] = excl;
    __syncthreads();
    if (threadIdx.x == 0) carry += wsum[0] + wsum[1] + wsum[2] + wsum[3];
    __syncthreads();
  }
  if (threadIdx.x == 0) bucketBase[BK] = carry;
}

// ---- P2 (512 thr): scatter packed (fine,payload) via LDS cursors; int4 reads.
__global__ __launch_bounds__(512) void p2_scatter(
    const int* __restrict__ vertex, const int* __restrict__ edges,
    const int* __restrict__ G, const int* __restrict__ bucketBase,
    unsigned* __restrict__ temp, int E, int BKE, int BK, int NCH) {
  __shared__ int curs[1024];
  int c = blockIdx.x;
  for (int b = threadIdx.x; b < BK; b += 512)
    curs[b] = bucketBase[b] + G[(size_t)b * NCH + c];
  __syncthreads();
  int s = c * CH, e_ = min(E, s + CH);
  int n4 = (e_ - s) >> 2;
  const int4* ep = (const int4*)(edges + s);
  const int4* vp = (const int4*)(vertex + s);
  for (int i = threadIdx.x; i < n4; i += 512) {
    int4 ee = ep[i], vv = vp[i];
    int p;
    p = atomicAdd(&curs[ee.x >> BSHIFT], 1);
    temp[p] = ((unsigned)(ee.x & (FINE - 1)) << PAYBITS) | (unsigned)vv.x;
    p = atomicAdd(&curs[BKE + (vv.x >> BSHIFT)], 1);
    temp[p] = ((unsigned)(vv.x & (FINE - 1)) << PAYBITS) | (unsigned)ee.x;
    p = atomicAdd(&curs[ee.y >> BSHIFT], 1);
    temp[p] = ((unsigned)(ee.y & (FINE - 1)) << PAYBITS) | (unsigned)vv.y;
    p = atomicAdd(&curs[BKE + (vv.y >> BSHIFT)], 1);
    temp[p] = ((unsigned)(vv.y & (FINE - 1)) << PAYBITS) | (unsigned)ee.y;
    p = atomicAdd(&curs[ee.z >> BSHIFT], 1);
    temp[p] = ((unsigned)(ee.z & (FINE - 1)) << PAYBITS) | (unsigned)vv.z;
    p = atomicAdd(&curs[BKE + (vv.z >> BSHIFT)], 1);
    temp[p] = ((unsigned)(vv.z & (FINE - 1)) << PAYBITS) | (unsigned)ee.z;
    p = atomicAdd(&curs[ee.w >> BSHIFT], 1);
    temp[p] = ((unsigned)(ee.w & (FINE - 1)) << PAYBITS) | (unsigned)vv.w;
    p = atomicAdd(&curs[BKE + (vv.w >> BSHIFT)], 1);
    temp[p] = ((unsigned)(vv.w & (FINE - 1)) << PAYBITS) | (unsigned)ee.w;
  }
  for (int i = s + (n4 << 2) + threadIdx.x; i < e_; i += 512) {
    int e = edges[i], v = vertex[i];
    int pE = atomicAdd(&curs[e >> BSHIFT], 1);
    temp[pE] = ((unsigned)(e & (FINE - 1)) << PAYBITS) | (unsigned)v;
    int pV = atomicAdd(&curs[BKE + (v >> BSHIFT)], 1);
    temp[pV] = ((unsigned)(v & (FINE - 1)) << PAYBITS) | (unsigned)e;
  }
}

// ---- P3: per-bucket fine counting sort -> off (inclusive ends) + perm.
// Pairs staged in LDS (cnt <= STAGE for this distribution; fallback kept).
__global__ __launch_bounds__(256) void p3_sort(
    const unsigned* __restrict__ temp, const int* __restrict__ bucketBase,
    int* __restrict__ off, int* __restrict__ perm, int BKE, int M, int N) {
  __shared__ int hist[FINE];
  __shared__ int pos[FINE];
  __shared__ int wsum[4];
  __shared__ unsigned pairsS[STAGE];
  int g = blockIdx.x;
  bool isE = g < BKE;
  int gg = isE ? g : g - BKE;
  int keyBase = gg << BSHIFT;
  int cap = isE ? M : N;
  int offBase = (isE ? 0 : M) + keyBase;
  int fineCount = min(FINE, cap - keyBase);
  int pairBase = bucketBase[g], pairEnd = bucketBase[g + 1];
  int cnt = pairEnd - pairBase;
  bool staged = cnt <= STAGE;

  for (int i = threadIdx.x; i < FINE; i += 256) hist[i] = 0;
  __syncthreads();
  if (staged) {
    for (int i = threadIdx.x; i < cnt; i += 256) {
      unsigned p = temp[pairBase + i];
      pairsS[i] = p;
      atomicAdd(&hist[p >> PAYBITS], 1);
    }
  } else {
    for (int i = threadIdx.x; i < cnt; i += 256)
      atomicAdd(&hist[temp[pairBase + i] >> PAYBITS], 1);
  }
  __syncthreads();

  int t2 = threadIdx.x * 2;
  int a0 = hist[t2], a1 = hist[t2 + 1];
  int tsum = a0 + a1;
  int lane = threadIdx.x & 63, wid = threadIdx.x >> 6;
  int inc = tsum;
  #pragma unroll
  for (int o = 1; o < 64; o <<= 1) {
    int t = __shfl_up(inc, o);
    if (lane >= o) inc += t;
  }
  if (lane == 63) wsum[wid] = inc;
  __syncthreads();
  int woff = 0;
  for (int w = 0; w < wid; ++w) woff += wsum[w];
  int excl = woff + inc - tsum;
  pos[t2] = excl; pos[t2 + 1] = excl + a0;
  __syncthreads();

  for (int f = threadIdx.x; f < fineCount; f += 256)
    off[offBase + f] = pairBase + pos[f] + hist[f];
  for (int f = threadIdx.x; f < FINE; f += 256) pos[f] += pairBase;
  __syncthreads();

  if (staged) {
    for (int i = threadIdx.x; i < cnt; i += 256) {
      unsigned p = pairsS[i];
      int q = atomicAdd(&pos[p >> PAYBITS], 1);
      perm[q] = (int)(p & PAYMASK);
    }
  } else {
    for (int i = threadIdx.x; i < cnt; i += 256) {
      unsigned p = temp[pairBase + i];
      int q = atomicAdd(&pos[p >> PAYBITS], 1);
      perm[q] = (int)(p & PAYMASK);
    }
  }
}

// ---- compute passes ----

// 8 hyperedges per wave, one per 8-lane group; 8 lanes × uint4 = 128B row.
__global__ __launch_bounds__(256) void k_edge(
    const unsigned short* __restrict__ Xb, const int* __restrict__ off,
    const int* __restrict__ perm, const float* __restrict__ dege,
    unsigned short* __restrict__ Xe, int M) {
  long long gid = (long long)blockIdx.x * 256 + threadIdx.x;
  int wv = (int)(gid >> 6);
  int lane = threadIdx.x & 63;
  int g = lane >> 3, li = lane & 7;     // 8 groups of 8 lanes
  int e = wv * 8 + g;
  bool valid = e < M;
  int start = 0, end = 0;
  if (valid) { start = e ? off[e - 1] : 0; end = off[e]; }
  int deg = end - start;
  int myidx = (valid && li < deg) ? perm[start + li] : 0;
  int jmax = min(deg, 8);
  int jw = jmax;
  jw = max(jw, __shfl_xor(jw, 8));
  jw = max(jw, __shfl_xor(jw, 16));
  jw = max(jw, __shfl_xor(jw, 32));
  const uint4* X4 = (const uint4*)Xb;   // 8 uint4 per 64-elem row
  float acc[8] = {0.f, 0.f, 0.f, 0.f, 0.f, 0.f, 0.f, 0.f};
  #pragma unroll 4
  for (int j = 0; j < jw; ++j) {
    int v0 = __shfl(myidx, (g << 3) + j);   // all 64 lanes active
    if (j < jmax) {
      uint4 a = X4[(size_t)v0 * 8 + li];
      acc[0] += b2f(a.x & 0xffffu); acc[1] += b2f(a.x >> 16);
      acc[2] += b2f(a.y & 0xffffu); acc[3] += b2f(a.y >> 16);
      acc[4] += b2f(a.z & 0xffffu); acc[5] += b2f(a.z >> 16);
      acc[6] += b2f(a.w & 0xffffu); acc[7] += b2f(a.w >> 16);
    }
  }
  for (int j = 8; j < deg; ++j) {           // tail (deg>8)
    int v0 = perm[start + j];
    uint4 a = X4[(size_t)v0 * 8 + li];
    acc[0] += b2f(a.x & 0xffffu); acc[1] += b2f(a.x >> 16);
    acc[2] += b2f(a.y & 0xffffu); acc[3] += b2f(a.y >> 16);
    acc[4] += b2f(a.z & 0xffffu); acc[5] += b2f(a.z >> 16);
    acc[6] += b2f(a.w & 0xffffu); acc[7] += b2f(a.w >> 16);
  }
  if (valid) {
    float s = dege[e] / fmaxf((float)deg, 1.0f);
    uint4 r;
    r.x = (unsigned)f2b(acc[0] * s) | ((unsigned)f2b(acc[1] * s) << 16);
    r.y = (unsigned)f2b(acc[2] * s) | ((unsigned)f2b(acc[3] * s) << 16);
    r.z = (unsigned)f2b(acc[4] * s) | ((unsigned)f2b(acc[5] * s) << 16);
    r.w = (unsigned)f2b(acc[6] * s) | ((unsigned)f2b(acc[7] * s) << 16);
    ((uint4*)Xe)[(size_t)e * 8 + li] = r;
  }
}

// Node aggregate: 8 nodes/wave, one per 8-lane group; 8 lanes × uint4 row
// loads; 2-register index prefetch (my0 for j<8, my1 for j in [8,16)).
__global__ __launch_bounds__(256) void k_nodeagg(
    const unsigned short* __restrict__ Xe, const int* __restrict__ off,
    const int* __restrict__ perm, const float* __restrict__ degv,
    unsigned short* __restrict__ xn, int N, int M) {
  long long gid = (long long)blockIdx.x * 256 + threadIdx.x;
  int wv = (int)(gid >> 6);
  int lane = threadIdx.x & 63;
  int g = lane >> 3, li = lane & 7;     // 8 groups of 8 lanes
  int node = wv * 8 + g;
  bool valid = node < N;
  int start = 0, end = 0;
  if (valid) { start = off[M + node - 1]; end = off[M + node]; }  // node0: off[M-1]==E
  int deg = end - start;
  int my0 = (valid && li < deg) ? perm[start + li] : 0;
  int my1 = (valid && 8 + li < deg) ? perm[start + 8 + li] : 0;
  int jmax0 = min(deg, 8);
  int jmax1 = min(max(deg - 8, 0), 8);
  int jw0 = jmax0, jw1 = jmax1;
  jw0 = max(jw0, __shfl_xor(jw0, 8)); jw1 = max(jw1, __shfl_xor(jw1, 8));
  jw0 = max(jw0, __shfl_xor(jw0, 16)); jw1 = max(jw1, __shfl_xor(jw1, 16));
  jw0 = max(jw0, __shfl_xor(jw0, 32)); jw1 = max(jw1, __shfl_xor(jw1, 32));
  const uint4* Xe4 = (const uint4*)Xe;  // 8 uint4 per 64-elem row
  float acc[8] = {0.f, 0.f, 0.f, 0.f, 0.f, 0.f, 0.f, 0.f};
  #pragma unroll 4
  for (int j = 0; j < jw0; ++j) {
    int e0 = __shfl(my0, (g << 3) + j);   // all 64 lanes active
    if (j < jmax0) {
      uint4 a = Xe4[(size_t)e0 * 8 + li];
      acc[0] += b2f(a.x & 0xffffu); acc[1] += b2f(a.x >> 16);
      acc[2] += b2f(a.y & 0xffffu); acc[3] += b2f(a.y >> 16);
      acc[4] += b2f(a.z & 0xffffu); acc[5] += b2f(a.z >> 16);
      acc[6] += b2f(a.w & 0xffffu); acc[7] += b2f(a.w >> 16);
    }
  }
  #pragma unroll 4
  for (int j = 0; j < jw1; ++j) {
    int e0 = __shfl(my1, (g << 3) + j);   // all 64 lanes active
    if (j < jmax1) {
      uint4 a = Xe4[(size_t)e0 * 8 + li];
      acc[0] += b2f(a.x & 0xffffu); acc[1] += b2f(a.x >> 16);
      acc[2] += b2f(a.y & 0xffffu); acc[3] += b2f(a.y >> 16);
      acc[4] += b2f(a.z & 0xffffu); acc[5] += b2f(a.z >> 16);
      acc[6] += b2f(a.w & 0xffffu); acc[7] += b2f(a.w >> 16);
    }
  }
  for (int j = 16; j < deg; ++j) {        // tail (deg>16), ~2% of nodes
    int e0 = perm[start + j];
    uint4 a = Xe4[(size_t)e0 * 8 + li];
    acc[0] += b2f(a.x & 0xffffu); acc[1] += b2f(a.x >> 16);
    acc[2] += b2f(a.y & 0xffffu); acc[3] += b2f(a.y >> 16);
    acc[4] += b2f(a.z & 0xffffu); acc[5] += b2f(a.z >> 16);
    acc[6] += b2f(a.w & 0xffffu); acc[7] += b2f(a.w >> 16);
  }
  float dv = valid ? degv[node] : 0.f;
  float ss = 0.f;
  #pragma unroll
  for (int i = 0; i < 8; ++i) { acc[i] *= dv; ss += acc[i] * acc[i]; }
  #pragma unroll
  for (int o = 1; o <= 4; o <<= 1) ss += __shfl_xor(ss, o);  // within group
  float sc = ss > 0.0f ? 1.0f / sqrtf(ss) : 0.0f;
  if (valid) {
    uint4 r;
    r.x = (unsigned)f2b(acc[0] * sc) | ((unsigned)f2b(acc[1] * sc) << 16);
    r.y = (unsigned)f2b(acc[2] * sc) | ((unsigned)f2b(acc[3] * sc) << 16);
    r.z = (unsigned)f2b(acc[4] * sc) | ((unsigned)f2b(acc[5] * sc) << 16);
    r.w = (unsigned)f2b(acc[6] * sc) | ((unsigned)f2b(acc[7] * sc) << 16);
    ((uint4*)xn)[(size_t)node * 8 + li] = r;
  }
}

// out[N x 128] = xn(bf16) @ W + b via mfma_f32_16x16x32_bf16.
// A frag: row = lane&15, k = (lane>>4)*8 + j. B frag: col = lane&15, same k.
// C/D: col = lane&15, row = (lane>>4)*4 + reg  [m89-verified].
#define WPAD 72
__global__ __launch_bounds__(256) void k_linear(
    const unsigned short* __restrict__ xn, const float* __restrict__ W,
    const float* __restrict__ bias, float* __restrict__ out, int N) {
  __shared__ unsigned short Wt[DOUT * WPAD];
  for (int i = threadIdx.x; i < DIN * DOUT; i += 256) {
    int k = i >> 7, c = i & 127;   // W[k][c]
    Wt[c * WPAD + k] = f2b(W[i]);
  }
  __syncthreads();
  int lane = threadIdx.x & 63;
  int wid = threadIdx.x >> 6;
  int r = lane & 15, h = lane >> 4;

  bf16x8 Bf[8][2];
  #pragma unroll
  for (int c = 0; c < 8; ++c) {
    #pragma unroll
    for (int ks = 0; ks < 2; ++ks) {
      int col = c * 16 + r;
      int k0 = ks * 32 + h * 8;
      Bf[c][ks] = *(const bf16x8*)&Wt[col * WPAD + k0];
    }
  }
  float bcol[8];
  #pragma unroll
  for (int c = 0; c < 8; ++c) bcol[c] = bias[c * 16 + r];

  int strips = (N + 15) >> 4;
  for (int s = blockIdx.x * 4 + wid; s < strips; s += gridDim.x * 4) {
    int row0 = s << 4;
    const unsigned short* xrow = xn + (size_t)(row0 + r) * DIN;
    bf16x8 a0 = *(const bf16x8*)&xrow[h * 8];
    bf16x8 a1 = *(const bf16x8*)&xrow[32 + h * 8];
    #pragma unroll
    for (int c = 0; c < 8; ++c) {
      f32x4 acc = {bcol[c], bcol[c], bcol[c], bcol[c]};
      acc = __builtin_amdgcn_mfma_f32_16x16x32_bf16(a0, Bf[c][0], acc, 0, 0, 0);
      acc = __builtin_amdgcn_mfma_f32_16x16x32_bf16(a1, Bf[c][1], acc, 0, 0, 0);
      #pragma unroll
      for (int q = 0; q < 4; ++q)
        out[(size_t)(row0 + h * 4 + q) * DOUT + c * 16 + r] = acc[q];
    }
  }
}

extern "C" void kernel_launch(void* const* d_in, const int* in_sizes, int n_in,
                              void* d_out, int out_size, void* d_ws, size_t ws_size,
                              hipStream_t stream) {
  const float* X      = (const float*)d_in[0];
  const int*   vertex = (const int*)d_in[1];
  const int*   edges  = (const int*)d_in[2];
  const float* dege   = (const float*)d_in[3];
  const float* degv   = (const float*)d_in[4];
  const float* W      = (const float*)d_in[5];
  const float* b      = (const float*)d_in[6];
  float* out = (float*)d_out;

  int N = in_sizes[0] / DIN;   // 100000
  int E = in_sizes[1];         // 1000000
  int M = in_sizes[3];         // 200000

  int NCH = (E + CH - 1) / CH;                 // 245
  int BKE = (M + FINE - 1) >> BSHIFT;          // 391
  int BKV = (N + FINE - 1) >> BSHIFT;          // 196
  int BK  = BKE + BKV;                         // 587

  // workspace layout; temp (dead after p3) aliases xn (written after p3)
  unsigned short* Xe = (unsigned short*)d_ws;               // M*64 bf16 (25.6 MB)
  unsigned short* Xb = Xe + (size_t)M * DIN;                // N*64 bf16 (12.8 MB)
  int*   off  = (int*)(Xb + (size_t)N * DIN);               // M+N
  int*   perm = off + (M + N);                              // 2E (8 MB)
  char*  R    = (char*)(perm + 2 * (size_t)E);
  unsigned*       temp = (unsigned*)R;                      // 2E u32 (8 MB)
  unsigned short* xn   = (unsigned short*)R;                // N*64 bf16 (12.8 MB)
  size_t rBytes = (size_t)2 * E * 4;
  size_t xBytes = (size_t)N * DIN * 2;
  char*  R2   = R + (rBytes > xBytes ? rBytes : xBytes);
  int*   G    = (int*)R2;                                   // BK*NCH (575 KB)
  int*   rowTot = G + (size_t)BK * NCH;                     // BK
  int*   bucketBase = rowTot + BK;                          // BK+1
  int*   done = bucketBase + BK + 1;                        // 1

  int total4 = N * DIN / 4;
  k_p1<<<NCH + XB, 512, 0, stream>>>(vertex, edges, G, X, Xb, done,
                                     E, BKE, BK, NCH, total4);
  k_p1b<<<BK, 256, 0, stream>>>(G, rowTot, bucketBase, done, NCH, BK);
  p2_scatter<<<NCH, 512, 0, stream>>>(vertex, edges, G, bucketBase, temp,
                                      E, BKE, BK, NCH);
  p3_sort<<<BK, 256, 0, stream>>>(temp, bucketBase, off, perm, BKE, M, N);

  int edgeBlocks = (M + 31) / 32;        // 8 edges/wave, 4 waves/block
  k_edge<<<edgeBlocks, 256, 0, stream>>>(Xb, off, perm, dege, Xe, M);

  int nodeWaves = (N + 7) / 8;           // 8 nodes/wave
  int nodeBlocks = (nodeWaves + 3) / 4;
  k_nodeagg<<<nodeBlocks, 256, 0, stream>>>(Xe, off, perm, degv, xn, N, M);

  int strips = (N + 15) >> 4;
  int linBlocks = (strips + 3) / 4;      // one strip per wave
  k_linear<<<linBlocks, 256, 0, stream>>>(xn, W, b, out, N);
}